// Round 21
// baseline (164.299 us; speedup 1.0000x reference)
//
#include <hip/hip_runtime.h>
#include <hip/hip_bf16.h>
#include <math.h>

#ifndef M_PI_F
#define M_PI_F 3.14159265358979323846f
#endif

static constexpr int Bb = 2, Tt = 1024, Dd = 1024, Hh = 16, DHh = 64, NFf = 256, Rr = 4096;
static constexpr int Mm = Bb * Tt;
static constexpr int CHK = 64, NCHK = Tt / CHK;  // attention chunking
static constexpr int QS = 3072;                  // fused qkv row stride

enum Epi { EPI_NONE = 0, EPI_RELU, EPI_QKV };

typedef __attribute__((ext_vector_type(8))) short bf16x8;
typedef __attribute__((ext_vector_type(4))) float f32x4;

__device__ inline float bf2f(unsigned short u) {
  union { unsigned int i; float f; } c;
  c.i = (unsigned int)u << 16;
  return c.f;
}

__device__ inline unsigned short f2bf(float f) {
  __hip_bfloat16 h = __float2bfloat16(f);
  return *(unsigned short*)&h;
}

// ---------------------------------------------------------------------------
// async global->LDS, 16B per lane. LDS dest is wave-uniform base; HW adds
// lane*16. Global address is per-lane.
// ---------------------------------------------------------------------------
__device__ inline void gload16(const short* g, short* l) {
  __builtin_amdgcn_global_load_lds(
      (const __attribute__((address_space(1))) unsigned int*)g,
      (__attribute__((address_space(3))) unsigned int*)l, 16, 0, 0);
}

// ---------------------------------------------------------------------------
// bf16 MFMA GEMM: C[M,N] = epi(A[M,K] @ BT[N,K]^T + bias)
// 128x128 tile, BK=64, 4 waves (2x2), each 64x64 via 4x4 frags of 16x16x32.
// - Double-buffered K-loop with counted vmcnt (r7). r18 A/B: single-buffer
//   at 4 blocks/CU REGRESSED — counted prefetch off the critical path beats
//   extra co-residency beyond 2 blocks/CU.
// - r20 RACE FIX (kept): sched_barrier(0) + s_waitcnt lgkmcnt(0) before the
//   done-reading s_barrier. s_barrier does NOT wait for outstanding LDS ops
//   and hipcc can sink register-only MFMAs past asm barriers (rule #18);
//   without the drain a wave could cross with ds_reads in flight while the
//   next-iteration global_load_lds overwrites the buffer (r17-r19 wobble).
// - LDS XOR bank-swizzle (rule #21 both-sides involution).
// - Bijective XCD swizzle (m204) for A-panel L2 reuse per XCD.
// - SPLITK: partial (fp32 Cf / bf16 Cb) at +z*M*N into DEDICATED buffers.
// ---------------------------------------------------------------------------
#define GSTAGE(bufsel, kk0)                                           \
  _Pragma("unroll") for (int si = 0; si < 4; ++si) {                  \
    const int s = wid + si * 4;                                       \
    gload16(A + (size_t)(m0 + s * 8 + srow) * ldk + (kk0) + skk,      \
            &lA[(bufsel) * 8192 + s * 512]);                          \
    gload16(BT + (size_t)(n0 + s * 8 + srow) * ldk + (kk0) + skk,     \
            &lB[(bufsel) * 8192 + s * 512]);                          \
  }

template <int EPI, int OUTBF, int SPLITK>
__global__ __launch_bounds__(256) void gemm_mfma(const short* __restrict__ A,
                                                 const short* __restrict__ BT,
                                                 const float* __restrict__ bias,
                                                 float* __restrict__ Cf,
                                                 __hip_bfloat16* __restrict__ Cb,
                                                 int M, int N, int ldk) {
  __shared__ short lA[2 * 128 * 64];
  __shared__ short lB[2 * 128 * 64];
  const int tid = threadIdx.x;
  const int wid = tid >> 6, lane = tid & 63;

  // XCD-aware bijective block swizzle (grids here always have nwg % 8 == 0)
  const int nwg = gridDim.x * gridDim.y;
  const int wg = blockIdx.y * gridDim.x + blockIdx.x;
  const int qq = nwg >> 3, rr = nwg & 7;
  const int xcd = wg & 7, idx = wg >> 3;
  const int wg2 = (xcd < rr ? xcd * (qq + 1) : rr * (qq + 1) + (xcd - rr) * qq) + idx;
  const int bx = wg2 % gridDim.x, by = wg2 / gridDim.x;

  const int m0 = by * 128, n0 = bx * 128;
  const int wm = (wid >> 1) * 64, wn = (wid & 1) * 64;
  const int srow = lane >> 3;                         // row within 8-row slab
  const int skk = (((lane & 7) ^ (lane >> 3)) << 3);  // swizzled k offset (elems)

  int kstart = 0, klen = ldk;
  if (SPLITK > 1) {
    klen = ldk / SPLITK;
    kstart = blockIdx.z * klen;
    if (OUTBF)
      Cb += (size_t)blockIdx.z * M * N;
    else
      Cf += (size_t)blockIdx.z * M * N;
  }
  const int kend = kstart + klen;

  f32x4 acc[4][4] = {};

  GSTAGE(0, kstart);  // prologue: 8 loads/wave in flight
  int cur = 0;
  for (int k0 = kstart; k0 < kend; k0 += 64) {
    if (k0 + 64 < kend) {
      GSTAGE(cur ^ 1, k0 + 64);                         // 16 in flight
      asm volatile("s_waitcnt vmcnt(8)" ::: "memory");  // oldest 8 (cur buf) done
    } else {
      asm volatile("s_waitcnt vmcnt(0)" ::: "memory");
    }
    asm volatile("s_barrier" ::: "memory");
    const short* bA = &lA[cur * 8192];
    const short* bB = &lB[cur * 8192];
#pragma unroll
    for (int kk = 0; kk < 2; ++kk) {
      const int krd = kk * 32 + (lane >> 4) * 8;
      const int rsel = lane & 15;
      const int kswz = krd ^ ((rsel & 7) << 3);  // same involution as store side
      bf16x8 af[4], bfr[4];
#pragma unroll
      for (int i = 0; i < 4; ++i) {
        af[i] = *(const bf16x8*)&bA[(wm + i * 16 + rsel) * 64 + kswz];
        bfr[i] = *(const bf16x8*)&bB[(wn + i * 16 + rsel) * 64 + kswz];
      }
#pragma unroll
      for (int i = 0; i < 4; ++i)
#pragma unroll
        for (int j = 0; j < 4; ++j)
          acc[i][j] = __builtin_amdgcn_mfma_f32_16x16x32_bf16(af[i], bfr[j], acc[i][j], 0, 0, 0);
    }
    // race fix: pin MFMA cluster, retire ALL LDS reads before signaling the
    // buffer reusable. vmcnt prefetch stays in flight (the dbuf win).
    __builtin_amdgcn_sched_barrier(0);
    asm volatile("s_waitcnt lgkmcnt(0)" ::: "memory");
    asm volatile("s_barrier" ::: "memory");
    cur ^= 1;
  }

  const int crow = (lane >> 4) * 4;
  const int ccol = lane & 15;
#pragma unroll
  for (int j = 0; j < 4; ++j) {
    const int col = n0 + wn + j * 16 + ccol;
    const float bv = bias ? bias[col] : 0.f;
#pragma unroll
    for (int i = 0; i < 4; ++i) {
#pragma unroll
      for (int r = 0; r < 4; ++r) {
        float v = acc[i][j][r] + bv;
        const int row = m0 + wm + i * 16 + crow + r;
        if (EPI == EPI_QKV) {
          const float vv = (col < 2048) ? fmaxf(v, 0.f) : v;
          Cb[(size_t)row * QS + col] = __float2bfloat16(vv);
        } else {
          if (EPI == EPI_RELU) v = fmaxf(v, 0.f);
          const size_t off = (size_t)row * N + col;
          if (OUTBF)
            Cb[off] = __float2bfloat16(v);
          else
            Cf[off] = v;
        }
      }
    }
  }
}

// ---------------------------------------------------------------------------
// 32x32 transpose-cast tile helper: W[K,N] f32 -> WT[N,K] bf16.
// ---------------------------------------------------------------------------
__device__ __forceinline__ void tc_tile(float (*tile)[33], const float* __restrict__ W,
                                        __hip_bfloat16* __restrict__ WT, int K, int N,
                                        int tlocal) {
  const int tilesN = N / 32;
  const int bk = (tlocal / tilesN) * 32, bn = (tlocal % tilesN) * 32;
  const int tx = threadIdx.x & 31, ty = threadIdx.x >> 5;  // 32x8
#pragma unroll
  for (int r = 0; r < 32; r += 8) tile[ty + r][tx] = W[(size_t)(bk + ty + r) * N + bn + tx];
  __syncthreads();
#pragma unroll
  for (int r = 0; r < 32; r += 8)
    WT[(size_t)(bn + ty + r) * K + bk + tx] = __float2bfloat16(tile[tx][ty + r]);
}

// ---------------------------------------------------------------------------
// Head kernel: W_amp / W_phi transpose-cast + x f32->bf16 cast.
// ---------------------------------------------------------------------------
__global__ __launch_bounds__(256) void tc_first(const float* __restrict__ W_amp,
                                                const float* __restrict__ W_phi,
                                                __hip_bfloat16* __restrict__ WTamp,
                                                __hip_bfloat16* __restrict__ WTphi,
                                                const float* __restrict__ x,
                                                __hip_bfloat16* __restrict__ xb) {
  __shared__ float tile[32][33];
  const int bid = blockIdx.x;
  if (bid >= 512) {
    const int i = ((bid - 512) * 256 + threadIdx.x) * 4;
    const float4 v = *(const float4*)&x[i];
    xb[i + 0] = __float2bfloat16(v.x);
    xb[i + 1] = __float2bfloat16(v.y);
    xb[i + 2] = __float2bfloat16(v.z);
    xb[i + 3] = __float2bfloat16(v.w);
    return;
  }
  if (bid < 256)
    tc_tile(tile, W_amp, WTamp, 1024, 256, bid);
  else
    tc_tile(tile, W_phi, WTphi, 1024, 256, bid - 256);
}

// ---------------------------------------------------------------------------
// amp/phi split-K reduce (4 bf16 partials) fused with activations and
// polar->cartesian. part layout: [4][M][512] bf16 (cols 0..255 amp, rest phi).
// ---------------------------------------------------------------------------
__global__ __launch_bounds__(256) void reduce_polar(const __hip_bfloat16* __restrict__ part,
                                                    const float* __restrict__ b_amp,
                                                    const float* __restrict__ b_phi,
                                                    __hip_bfloat16* __restrict__ outr,
                                                    __hip_bfloat16* __restrict__ outi) {
  const int idx = blockIdx.x * 256 + threadIdx.x;  // [0, M*NF)
  const int row = idx >> 8, c = idx & 255;
  const size_t MN = (size_t)Mm * 512;
  const size_t pa = (size_t)row * 512 + c;
  const unsigned short* pu = (const unsigned short*)part;
  float a = bf2f(pu[pa]) + bf2f(pu[pa + MN]) + bf2f(pu[pa + 2 * MN]) + bf2f(pu[pa + 3 * MN]) +
            b_amp[c];
  float ph = bf2f(pu[pa + 256]) + bf2f(pu[pa + 256 + MN]) + bf2f(pu[pa + 256 + 2 * MN]) +
             bf2f(pu[pa + 256 + 3 * MN]) + b_phi[c];
  a = (a > 0.f) ? (a + log1pf(expf(-a))) : log1pf(expf(a));
  ph = M_PI_F * tanhf(ph);
  float s, co;
  sincosf(ph, &s, &co);
  outr[idx] = __float2bfloat16(a * co);
  outi[idx] = __float2bfloat16(a * s);
}

// ---------------------------------------------------------------------------
// FUSED: resonator scan (blocks 0..63) || transpose-cast of the 6 remaining
// weights (blocks 64..12095) — independent work backfills the machine (r11).
// Scan: TIME-CHUNK PARALLEL (r6): contraction >= sigmoid(2.0)=0.881/step
// makes a 128-step warm-up from X=0 exact below bf16 quantization.
// ---------------------------------------------------------------------------
static constexpr int RES_P = 16;
static constexpr int RES_TC = 128;  // chunk length
static constexpr int RES_W = 128;   // warm-up length

#define RES_LOAD(buf_r, buf_i, tg)                                        \
  if ((tg) < cend) {                                                      \
    _Pragma("unroll") for (int i = 0; i < RES_P; ++i) {                   \
      buf_r[i] = __bfloat162float(ur[bbase + (size_t)((tg) + i) * NFf]);  \
      buf_i[i] = __bfloat162float(ui[bbase + (size_t)((tg) + i) * NFf]);  \
    }                                                                     \
  }

#define RES_STEP(buf_r, buf_i, tg)                                      \
  {                                                                      \
    const bool wr_ = (tg) >= cstart;                                     \
    _Pragma("unroll") for (int i = 0; i < RES_P; ++i) {                  \
      const float pr = fmaf(ar, Xr, fmaf(-ai, Xi, buf_r[i]));            \
      const float pim = fmaf(ar, Xi, fmaf(ai, Xr, buf_i[i]));            \
      const float mag = __builtin_amdgcn_sqrtf(fmaf(pr, pr, pim * pim)); \
      const float g = __builtin_amdgcn_rcpf(1.f + __expf(th - mag));     \
      Xr = pr * g;                                                       \
      Xi = pim * g;                                                      \
      if (wr_) {                                                         \
        const size_t fb = ((size_t)b * Tt + (tg) + i) * (3 * NFf);       \
        featb[fb + f] = __float2bfloat16(Xr);                            \
        featb[fb + NFf + f] = __float2bfloat16(Xi);                      \
        featb[fb + 2 * NFf + f] = __float2bfloat16(mag * g);             \
      }                                                                  \
    }                                                                    \
  }

struct STDesc {
  const float* src[6];
  __hip_bfloat16* dst[6];
  const __hip_bfloat16* ur;
  const __hip_bfloat16* ui;
  const float* omega;
  const float* ret_logit;
  const float* theta;
  __hip_bfloat16* featb;
};

__global__ __launch_bounds__(256) void scan_and_tc(STDesc d) {
  __shared__ float tile[32][33];
  const int bid = blockIdx.x;
  if (bid < 64) {
    if (threadIdx.x >= 64) return;  // scan uses 64 lanes; no barriers below
    const int tc = bid & 7;
    const int fs = (bid >> 3) & 3;
    const int b = bid >> 5;
    const int f = fs * 64 + threadIdx.x;
    const int cstart = tc * RES_TC;
    const int cend = cstart + RES_TC;
    const int tbeg = (cstart >= RES_W) ? cstart - RES_W : 0;
    const __hip_bfloat16* ur = d.ur;
    const __hip_bfloat16* ui = d.ui;
    __hip_bfloat16* featb = d.featb;
    const float dec = 1.f / (1.f + __expf(-d.ret_logit[f]));
    float so, co;
    sincosf(d.omega[f], &so, &co);
    const float ar = dec * co, ai = dec * so;
    const float th = d.theta[f];
    const size_t bbase = (size_t)b * Tt * NFf + f;
    float Xr = 0.f, Xi = 0.f;
    float Ar[RES_P], Ai[RES_P], Br[RES_P], Bi[RES_P];
    RES_LOAD(Ar, Ai, tbeg);
    for (int t0 = tbeg; t0 < cend; t0 += 2 * RES_P) {
      RES_LOAD(Br, Bi, t0 + RES_P);
      RES_STEP(Ar, Ai, t0);
      RES_LOAD(Ar, Ai, t0 + 2 * RES_P);
      RES_STEP(Br, Bi, t0 + RES_P);
    }
    return;
  }
  // transpose-cast region: W_feat, Wq, Wk, Wv, W1, W2
  constexpr int KS[6] = {768, 1024, 1024, 1024, 1024, 4096};
  constexpr int NS[6] = {1024, 1024, 1024, 1024, 4096, 1024};
  constexpr int CUM[7] = {0, 768, 1792, 2816, 3840, 7936, 12032};
  const int t = bid - 64;
  int w = 0;
#pragma unroll
  for (int i = 0; i < 6; ++i)
    if (t >= CUM[i + 1]) w = i + 1;
  tc_tile(tile, d.src[w], d.dst[w], KS[w], NS[w], t - CUM[w]);
}

// ---------------------------------------------------------------------------
// Attention phase A: per-chunk KV outer-product sums (fp32 S out — r21:
// bf16 S storage was a correlated 0.4% error on the dominant Q@P term and
// pushed absmax to 99.6% of threshold) and fp32 k-sums.
// ---------------------------------------------------------------------------
__global__ __launch_bounds__(256) void attn_chunk_kv(const __hip_bfloat16* __restrict__ k,
                                                     const __hip_bfloat16* __restrict__ v,
                                                     float* __restrict__ S,
                                                     float* __restrict__ Ksum) {
  __shared__ float Ks[64][68], Vs[64][68];
  const int g = blockIdx.x;
  const int j = g & (NCHK - 1), bh = g >> 4;
  const int b = bh >> 4, h = bh & (Hh - 1);
  const int tid = threadIdx.x;
  const size_t rowbase = (size_t)(b * Tt + j * CHK) * QS + h * DHh;
  const unsigned short* ku = (const unsigned short*)k;
  const unsigned short* vu = (const unsigned short*)v;
  for (int l = tid; l < 4096; l += 256) {
    const int s = l >> 6, d = l & 63;
    Ks[s][d] = bf2f(ku[rowbase + (size_t)s * QS + d]);
    Vs[s][d] = bf2f(vu[rowbase + (size_t)s * QS + d]);
  }
  __syncthreads();
  const int d0 = tid & 63, eb = tid >> 6, e0 = eb * 16;
  float4 acc4[4] = {};
  float ks = 0.f;
  for (int s = 0; s < 64; ++s) {
    const float kd = Ks[s][d0];
    ks += kd;
#pragma unroll
    for (int i = 0; i < 4; ++i) {
      const float4 v4 = *(const float4*)&Vs[s][e0 + 4 * i];
      acc4[i].x = fmaf(kd, v4.x, acc4[i].x);
      acc4[i].y = fmaf(kd, v4.y, acc4[i].y);
      acc4[i].z = fmaf(kd, v4.z, acc4[i].z);
      acc4[i].w = fmaf(kd, v4.w, acc4[i].w);
    }
  }
  float* Sg = S + (size_t)g * 4096 + (size_t)d0 * 64 + e0;
#pragma unroll
  for (int i = 0; i < 4; ++i) *(float4*)&Sg[4 * i] = acc4[i];
  if (eb == 0) Ksum[(size_t)g * 64 + d0] = ks;
}

// ---------------------------------------------------------------------------
// Attention phase B: EXCLUSIVE prefix over the 16 chunks per (b,h).
// FULLY PARALLEL (r10): one thread per chain; all fp32 (r21).
// ---------------------------------------------------------------------------
__global__ __launch_bounds__(256) void attn_prefix(float* __restrict__ S,
                                                   float* __restrict__ Ksum) {
  const int bid = blockIdx.x;
  const int tid = threadIdx.x;
  if (bid < 512) {
    const int bh = bid >> 4, r = bid & 15;
    const int de = r * 256 + tid;
    const size_t base = (size_t)bh * (NCHK * 4096) + de;
    float vv[NCHK];
#pragma unroll
    for (int j = 0; j < NCHK; ++j) vv[j] = S[base + (size_t)j * 4096];
    float run = 0.f;
#pragma unroll
    for (int j = 0; j < NCHK; ++j) {
      const float tmp = vv[j];
      S[base + (size_t)j * 4096] = run;
      run += tmp;
    }
  } else {
    const int cid = (bid - 512) * 256 + tid;  // [0, 2048)
    const int bh = cid >> 6, d = cid & 63;
    const size_t base = (size_t)bh * (NCHK * 64) + d;
    float vv[NCHK];
#pragma unroll
    for (int j = 0; j < NCHK; ++j) vv[j] = Ksum[base + (size_t)j * 64];
    float run = 0.f;
#pragma unroll
    for (int j = 0; j < NCHK; ++j) {
      const float tmp = vv[j];
      Ksum[base + (size_t)j * 64] = run;
      run += tmp;
    }
  }
}

// ---------------------------------------------------------------------------
// Attention phase C + fused per-head layernorm — FULLY MFMA.
// Stage 1 (QK^T): frags direct from global; masked scores stored as
// DOUBLE-BF16 (hi + lo) At[t][s] (r17).
// Stage 2: num[t][e] = At @ V + Q @ P via MFMA. r21: P is fp32 in global and
// consumed as DOUBLE-BF16 (hi + lo) too — bf16-P storage was the dominant
// correlated error. V staged transposed; 8 MFMAs per ct.
// Same operand convention as gemm_mfma. LN epilogue: row t spans 16
// consecutive lanes -> shfl_xor 1/2/4/8. All barriers are __syncthreads().
// ---------------------------------------------------------------------------
__global__ __launch_bounds__(256) void attn_out(const __hip_bfloat16* __restrict__ q,
                                                const __hip_bfloat16* __restrict__ k,
                                                const __hip_bfloat16* __restrict__ v,
                                                const float* __restrict__ S,
                                                const float* __restrict__ Ksum,
                                                const float* __restrict__ lnw,
                                                const float* __restrict__ lnb,
                                                __hip_bfloat16* __restrict__ yhb) {
  __shared__ unsigned short Atb[64][72];  // masked scores hi [t][s] bf16
  __shared__ unsigned short Atl[64][72];  // masked scores lo [t][s] bf16
  __shared__ unsigned short Vt[64][72];   // V^T [e][s] bf16
  __shared__ unsigned short Pth[64][72];  // P^T hi [e][d] bf16
  __shared__ unsigned short Ptl[64][72];  // P^T lo [e][d] bf16
  __shared__ float denp[4][64];
  __shared__ float dens[64];
  const int g = blockIdx.x;
  const int j = g & (NCHK - 1), bh = g >> 4;
  const int b = bh >> 4, h = bh & (Hh - 1);
  const int tid = threadIdx.x;
  const size_t rowbase = (size_t)(b * Tt + j * CHK) * QS + h * DHh;
  const unsigned short* qu = (const unsigned short*)q;
  const unsigned short* ku = (const unsigned short*)k;
  const unsigned short* vu = (const unsigned short*)v;
  const float* Pg = S + (size_t)g * 4096;

  // entry: stage V^T (bf16 copy) and P^T as hi/lo double-bf16 from fp32
  for (int l = tid; l < 4096; l += 256) {
    const int s = l >> 6, e = l & 63;
    Vt[e][s] = vu[rowbase + (size_t)s * QS + e];
    const float pv = Pg[l];  // l = d*64+e, d = l>>6 -> store Pt[e][d]
    const unsigned short ph = f2bf(pv);
    Pth[e][s] = ph;
    Ptl[e][s] = f2bf(pv - bf2f(ph));
  }
  // --- stage 1: QK^T via MFMA, fragments direct from global ---
  {
    const int w4 = tid >> 6, ln = tid & 63;
    const int fr = ln & 15;
    const int kh = ln >> 4;
    const unsigned short* kr = ku + rowbase + (size_t)(w4 * 16 + fr) * QS + kh * 8;
    const bf16x8 a0 = *(const bf16x8*)&kr[0];
    const bf16x8 a1 = *(const bf16x8*)&kr[32];
    f32x4 accQK[4] = {};
#pragma unroll
    for (int tt = 0; tt < 4; ++tt) {
      const unsigned short* qr = qu + rowbase + (size_t)(tt * 16 + fr) * QS + kh * 8;
      const bf16x8 b0 = *(const bf16x8*)&qr[0];
      const bf16x8 b1 = *(const bf16x8*)&qr[32];
      accQK[tt] = __builtin_amdgcn_mfma_f32_16x16x32_bf16(a0, b0, accQK[tt], 0, 0, 0);
      accQK[tt] = __builtin_amdgcn_mfma_f32_16x16x32_bf16(a1, b1, accQK[tt], 0, 0, 0);
    }
    // mask (keep s <= t), write hi/lo At[t][s], per-wave den partials
#pragma unroll
    for (int tt = 0; tt < 4; ++tt) {
      const int t = tt * 16 + fr;
      float dp = 0.f;
#pragma unroll
      for (int r = 0; r < 4; ++r) {
        const int s = w4 * 16 + kh * 4 + r;
        const float val = (s <= t) ? accQK[tt][r] : 0.f;
        const unsigned short hv = f2bf(val);
        Atb[t][s] = hv;
        Atl[t][s] = f2bf(val - bf2f(hv));
        dp += val;
      }
      dp += __shfl_xor(dp, 16);
      dp += __shfl_xor(dp, 32);
      if (ln < 16) denp[w4][t] = dp;
    }
  }
  __syncthreads();
  // --- den: qpk (q direct from global, sg-split) + denp sums ---
  {
    const int t = tid >> 2, sg = tid & 3;
    const float* pk = Ksum + (size_t)g * 64;
    const unsigned short* qr = qu + rowbase + (size_t)t * QS + sg * 16;
    float qpk = 0.f;
#pragma unroll
    for (int i = 0; i < 16; ++i) qpk = fmaf(bf2f(qr[i]), pk[sg * 16 + i], qpk);
    qpk += __shfl_xor(qpk, 1);
    qpk += __shfl_xor(qpk, 2);
    if (sg == 0)
      dens[t] = denp[0][t] + denp[1][t] + denp[2][t] + denp[3][t] + qpk + 1e-6f;
  }
  __syncthreads();
  // --- stage 2: num = At @ V + Q @ P via MFMA (hi+lo for At AND P) ---
  const int w = tid >> 6, ln = tid & 63;
  const int fr = ln & 15;
  const int kh = ln >> 4;
  const bf16x8 sa0 = *(const bf16x8*)&Atb[w * 16 + fr][kh * 8];
  const bf16x8 sa1 = *(const bf16x8*)&Atb[w * 16 + fr][kh * 8 + 32];
  const bf16x8 la0 = *(const bf16x8*)&Atl[w * 16 + fr][kh * 8];
  const bf16x8 la1 = *(const bf16x8*)&Atl[w * 16 + fr][kh * 8 + 32];
  const unsigned short* q2 = qu + rowbase + (size_t)(w * 16 + fr) * QS + kh * 8;
  const bf16x8 qa0 = *(const bf16x8*)&q2[0];
  const bf16x8 qa1 = *(const bf16x8*)&q2[32];
  f32x4 acc2[4] = {};
#pragma unroll
  for (int ct = 0; ct < 4; ++ct) {
    const bf16x8 vb0 = *(const bf16x8*)&Vt[ct * 16 + fr][kh * 8];
    const bf16x8 vb1 = *(const bf16x8*)&Vt[ct * 16 + fr][kh * 8 + 32];
    const bf16x8 ph0 = *(const bf16x8*)&Pth[ct * 16 + fr][kh * 8];
    const bf16x8 ph1 = *(const bf16x8*)&Pth[ct * 16 + fr][kh * 8 + 32];
    const bf16x8 pl0 = *(const bf16x8*)&Ptl[ct * 16 + fr][kh * 8];
    const bf16x8 pl1 = *(const bf16x8*)&Ptl[ct * 16 + fr][kh * 8 + 32];
    acc2[ct] = __builtin_amdgcn_mfma_f32_16x16x32_bf16(sa0, vb0, acc2[ct], 0, 0, 0);
    acc2[ct] = __builtin_amdgcn_mfma_f32_16x16x32_bf16(sa1, vb1, acc2[ct], 0, 0, 0);
    acc2[ct] = __builtin_amdgcn_mfma_f32_16x16x32_bf16(la0, vb0, acc2[ct], 0, 0, 0);
    acc2[ct] = __builtin_amdgcn_mfma_f32_16x16x32_bf16(la1, vb1, acc2[ct], 0, 0, 0);
    acc2[ct] = __builtin_amdgcn_mfma_f32_16x16x32_bf16(qa0, ph0, acc2[ct], 0, 0, 0);
    acc2[ct] = __builtin_amdgcn_mfma_f32_16x16x32_bf16(qa1, ph1, acc2[ct], 0, 0, 0);
    acc2[ct] = __builtin_amdgcn_mfma_f32_16x16x32_bf16(qa0, pl0, acc2[ct], 0, 0, 0);
    acc2[ct] = __builtin_amdgcn_mfma_f32_16x16x32_bf16(qa1, pl1, acc2[ct], 0, 0, 0);
  }
  // --- epilogue: divide by den, per-head LN (row t in 16 consecutive lanes) ---
  unsigned short* yb = (unsigned short*)yhb;
#pragma unroll
  for (int r = 0; r < 4; ++r) {
    const int t = w * 16 + kh * 4 + r;
    const float inv = 1.f / dens[t];
    float o[4];
    float s1 = 0.f, s2 = 0.f;
#pragma unroll
    for (int ct = 0; ct < 4; ++ct) {
      o[ct] = acc2[ct][r] * inv;
      s1 += o[ct];
      s2 += o[ct] * o[ct];
    }
#pragma unroll
    for (int m = 1; m < 16; m <<= 1) {
      s1 += __shfl_xor(s1, m);
      s2 += __shfl_xor(s2, m);
    }
    const float mean = s1 * (1.f / 64.f);
    const float var = s2 * (1.f / 64.f) - mean * mean;
    const float rsv = rsqrtf(var + 1e-5f);
    unsigned short* yg = yb + (size_t)(b * Tt + j * CHK + t) * Dd + h * DHh;
#pragma unroll
    for (int ct = 0; ct < 4; ++ct) {
      const int e = ct * 16 + fr;
      const float rr = (o[ct] - mean) * rsv * lnw[h * DHh + e] + lnb[h * DHh + e];
      yg[e] = f2bf(rr);
    }
  }
}

// ---------------------------------------------------------------------------
// Fused FFN2-reduce (4 bf16 split-K partials) + bias + relu + residual +
// final layernorm over D=1024.
// ---------------------------------------------------------------------------
__global__ __launch_bounds__(256) void final_ln(const float* __restrict__ x,
                                                const __hip_bfloat16* __restrict__ part,
                                                const float* __restrict__ b2,
                                                const float* __restrict__ w,
                                                const float* __restrict__ bb,
                                                float* __restrict__ out) {
  __shared__ float r1[4], r2[4];
  const int row = blockIdx.x;
  const int tid = threadIdx.x;
  const size_t off = (size_t)row * Dd + tid * 4;
  const size_t MN = (size_t)Mm * Dd;
  float acc4[4] = {0.f, 0.f, 0.f, 0.f};
#pragma unroll
  for (int z = 0; z < 4; ++z) {
    const ushort4 u = *(const ushort4*)&part[off + (size_t)z * MN];
    acc4[0] += bf2f(u.x);
    acc4[1] += bf2f(u.y);
    acc4[2] += bf2f(u.z);
    acc4[3] += bf2f(u.w);
  }
  const float4 bv = *(const float4*)&b2[tid * 4];
  const float4 xa = *(const float4*)&x[off];
  float z[4];
  z[0] = xa.x + fmaxf(acc4[0] + bv.x, 0.f);
  z[1] = xa.y + fmaxf(acc4[1] + bv.y, 0.f);
  z[2] = xa.z + fmaxf(acc4[2] + bv.z, 0.f);
  z[3] = xa.w + fmaxf(acc4[3] + bv.w, 0.f);
  float s1 = z[0] + z[1] + z[2] + z[3];
  float s2 = z[0] * z[0] + z[1] * z[1] + z[2] * z[2] + z[3] * z[3];
#pragma unroll
  for (int o = 1; o < 64; o <<= 1) {
    s1 += __shfl_xor(s1, o);
    s2 += __shfl_xor(s2, o);
  }
  const int wid = tid >> 6;
  if ((tid & 63) == 0) {
    r1[wid] = s1;
    r2[wid] = s2;
  }
  __syncthreads();
  const float t1 = r1[0] + r1[1] + r1[2] + r1[3];
  const float t2 = r2[0] + r2[1] + r2[2] + r2[3];
  const float mu = t1 * (1.f / Dd);
  const float var = t2 * (1.f / Dd) - mu * mu;
  const float rsv = rsqrtf(var + 1e-5f);
  float4 o4;
  float* op = &o4.x;
#pragma unroll
  for (int jj = 0; jj < 4; ++jj) op[jj] = (z[jj] - mu) * rsv * w[tid * 4 + jj] + bb[tid * 4 + jj];
  *(float4*)&out[off] = o4;
}

// ---------------------------------------------------------------------------
extern "C" void kernel_launch(void* const* d_in, const int* in_sizes, int n_in,
                              void* d_out, int out_size, void* d_ws, size_t ws_size,
                              hipStream_t stream) {
  const float* x = (const float*)d_in[0];
  const float* W_amp = (const float*)d_in[1];
  const float* b_amp = (const float*)d_in[2];
  const float* W_phi = (const float*)d_in[3];
  const float* b_phi = (const float*)d_in[4];
  const float* omega = (const float*)d_in[5];
  const float* ret_logit = (const float*)d_in[6];
  const float* theta = (const float*)d_in[7];
  const float* W_feat = (const float*)d_in[8];
  const float* b_feat = (const float*)d_in[9];
  const float* Wq = (const float*)d_in[10];
  const float* Wk = (const float*)d_in[11];
  const float* Wv = (const float*)d_in[12];
  const float* lnh_w = (const float*)d_in[13];
  const float* lnh_b = (const float*)d_in[14];
  const float* W1 = (const float*)d_in[15];
  const float* b1 = (const float*)d_in[16];
  const float* W2 = (const float*)d_in[17];
  const float* b2 = (const float*)d_in[18];
  const float* ln_w = (const float*)d_in[19];
  const float* ln_b = (const float*)d_in[20];

  // ---- workspace bump allocator (256B aligned); dedicated buffers ----
  char* p = (char*)d_ws;
  auto alloc = [&](size_t bytes) {
    char* r = p;
    p += (bytes + 255) & ~(size_t)255;
    return r;
  };
  __hip_bfloat16* xb = (__hip_bfloat16*)alloc((size_t)Mm * Dd * 2);   // later: featb
  __hip_bfloat16* urh = (__hip_bfloat16*)alloc((size_t)Mm * NFf * 2);
  __hip_bfloat16* uih = (__hip_bfloat16*)alloc((size_t)Mm * NFf * 2);
  __hip_bfloat16* WTamp = (__hip_bfloat16*)alloc((size_t)NFf * Dd * 2);  // +WTphi contiguous
  __hip_bfloat16* WTphi = (__hip_bfloat16*)alloc((size_t)NFf * Dd * 2);
  __hip_bfloat16* WTfeat = (__hip_bfloat16*)alloc((size_t)Dd * 3 * NFf * 2);
  __hip_bfloat16* WTq = (__hip_bfloat16*)alloc((size_t)Dd * Dd * 2);  // +k+v contiguous
  __hip_bfloat16* WTk = (__hip_bfloat16*)alloc((size_t)Dd * Dd * 2);
  __hip_bfloat16* WTv = (__hip_bfloat16*)alloc((size_t)Dd * Dd * 2);
  __hip_bfloat16* WT1 = (__hip_bfloat16*)alloc((size_t)Rr * Dd * 2);
  __hip_bfloat16* WT2 = (__hip_bfloat16*)alloc((size_t)Dd * Rr * 2);
  __hip_bfloat16* hb = (__hip_bfloat16*)alloc((size_t)Mm * Dd * 2);
  __hip_bfloat16* qkvb = (__hip_bfloat16*)alloc((size_t)Mm * QS * 2);  // 12 MB
  __hip_bfloat16* yhb = (__hip_bfloat16*)alloc((size_t)Mm * Dd * 2);   // 4 MB
  float* S = (float*)alloc((size_t)Bb * Hh * NCHK * 4096 * 4);         // 8 MB fp32 (r21)
  float* Ksum = (float*)alloc((size_t)Bb * Hh * NCHK * 64 * 4);
  __hip_bfloat16* f1b = (__hip_bfloat16*)alloc((size_t)Mm * Rr * 2);   // 16 MB
  __hip_bfloat16* pamp = (__hip_bfloat16*)alloc((size_t)4 * Mm * 512 * 2);   // 8 MB dedicated
  __hip_bfloat16* pffn2 = (__hip_bfloat16*)alloc((size_t)4 * Mm * Dd * 2);   // 16 MB dedicated

  __hip_bfloat16* featb = xb;  // xb dead after ampphi GEMM (stream-ordered)
  const __hip_bfloat16* q = qkvb;
  const __hip_bfloat16* k = qkvb + 1024;
  const __hip_bfloat16* v = qkvb + 2048;
  float* out = (float*)d_out;

  const dim3 blk(256);

  // 0: amp/phi weight transposes + x cast (what the first GEMM needs)
  tc_first<<<dim3(2560), blk, 0, stream>>>(W_amp, W_phi, WTamp, WTphi, x, xb);

  // 1: fused amp/phi projection, split-K=4 (256 blocks, bf16 partials), then
  //    fused reduce + softplus/tanh + polar -> bf16 u
  gemm_mfma<EPI_NONE, 1, 4><<<dim3(512 / 128, Mm / 128, 4), blk, 0, stream>>>(
      (const short*)xb, (const short*)WTamp, nullptr, nullptr, pamp, Mm, 512, Dd);
  reduce_polar<<<dim3(Mm * NFf / 256), blk, 0, stream>>>(pamp, b_amp, b_phi, urh, uih);

  // 2: FUSED resonator scan (64 blocks) || remaining weight transposes
  STDesc st;
  st.src[0] = W_feat; st.dst[0] = WTfeat;
  st.src[1] = Wq; st.dst[1] = WTq;
  st.src[2] = Wk; st.dst[2] = WTk;
  st.src[3] = Wv; st.dst[3] = WTv;
  st.src[4] = W1; st.dst[4] = WT1;
  st.src[5] = W2; st.dst[5] = WT2;
  st.ur = urh; st.ui = uih;
  st.omega = omega; st.ret_logit = ret_logit; st.theta = theta;
  st.featb = featb;
  scan_and_tc<<<dim3(64 + 12032), blk, 0, stream>>>(st);

  // 3: feat projection -> h (bf16)
  gemm_mfma<EPI_RELU, 1, 0><<<dim3(Dd / 128, Mm / 128), blk, 0, stream>>>(
      (const short*)featb, (const short*)WTfeat, b_feat, nullptr, hb, Mm, Dd, 3 * NFf);

  // 4: fused q,k,v projection -> bf16 qkvb (384 blocks)
  gemm_mfma<EPI_QKV, 1, 0><<<dim3(QS / 128, Mm / 128), blk, 0, stream>>>(
      (const short*)hb, (const short*)WTq, nullptr, nullptr, qkvb, Mm, QS, Dd);

  // 5: chunked causal linear attention (+ fused per-head LN in attn_out)
  attn_chunk_kv<<<dim3(Bb * Hh * NCHK), blk, 0, stream>>>(k, v, S, Ksum);
  attn_prefix<<<dim3(520), blk, 0, stream>>>(S, Ksum);
  attn_out<<<dim3(Bb * Hh * NCHK), blk, 0, stream>>>(q, k, v, S, Ksum, lnh_w, lnh_b, yhb);

  // 6: FFN1 -> f1b (bf16); 512 blocks = 2 blocks/CU (dbuf LDS cap)
  gemm_mfma<EPI_RELU, 1, 0><<<dim3(Rr / 128, Mm / 128), blk, 0, stream>>>(
      (const short*)yhb, (const short*)WT1, b1, nullptr, f1b, Mm, Rr, Dd);

  // 7: FFN2 split-K=4, bf16 partials -> pffn2; 512 blocks = 2 blocks/CU
  gemm_mfma<EPI_NONE, 1, 4><<<dim3(Dd / 128, Mm / 128, 4), blk, 0, stream>>>(
      (const short*)f1b, (const short*)WT2, nullptr, nullptr, pffn2, Mm, Dd, Rr);

  // 8: fused reduce(4x bf16) + bias + relu + residual + final layernorm
  final_ln<<<dim3(Mm), blk, 0, stream>>>(x, pffn2, b2, ln_w, ln_b, out);
}

// Round 22
// 159.199 us; speedup vs baseline: 1.0320x; 1.0320x over previous
//
#include <hip/hip_runtime.h>
#include <hip/hip_bf16.h>
#include <math.h>

#ifndef M_PI_F
#define M_PI_F 3.14159265358979323846f
#endif

static constexpr int Bb = 2, Tt = 1024, Dd = 1024, Hh = 16, DHh = 64, NFf = 256, Rr = 4096;
static constexpr int Mm = Bb * Tt;
static constexpr int CHK = 64, NCHK = Tt / CHK;  // attention chunking
static constexpr int QS = 3072;                  // fused qkv row stride

enum Epi { EPI_NONE = 0, EPI_RELU, EPI_QKV };

typedef __attribute__((ext_vector_type(8))) short bf16x8;
typedef __attribute__((ext_vector_type(4))) float f32x4;

__device__ inline float bf2f(unsigned short u) {
  union { unsigned int i; float f; } c;
  c.i = (unsigned int)u << 16;
  return c.f;
}

__device__ inline unsigned short f2bf(float f) {
  __hip_bfloat16 h = __float2bfloat16(f);
  return *(unsigned short*)&h;
}

// ---------------------------------------------------------------------------
// async global->LDS, 16B per lane. LDS dest is wave-uniform base; HW adds
// lane*16. Global address is per-lane.
// ---------------------------------------------------------------------------
__device__ inline void gload16(const short* g, short* l) {
  __builtin_amdgcn_global_load_lds(
      (const __attribute__((address_space(1))) unsigned int*)g,
      (__attribute__((address_space(3))) unsigned int*)l, 16, 0, 0);
}

// ---------------------------------------------------------------------------
// bf16 MFMA GEMM: C[M,N] = epi(A[M,K] @ BT[N,K]^T + bias)
// 128x128 tile, BK=64, 4 waves (2x2), each 64x64 via 4x4 frags of 16x16x32.
// - Double-buffered K-loop with counted vmcnt (r7). r18 A/B: single-buffer
//   at 4 blocks/CU REGRESSED — counted prefetch off the critical path beats
//   extra co-residency beyond 2 blocks/CU.
// - r20 RACE FIX (kept): sched_barrier(0) + s_waitcnt lgkmcnt(0) before the
//   done-reading s_barrier. s_barrier does NOT wait for outstanding LDS ops
//   and hipcc can sink register-only MFMAs past asm barriers (rule #18);
//   without the drain a wave could cross with ds_reads in flight while the
//   next-iteration global_load_lds overwrites the buffer (r17-r19 wobble).
// - LDS XOR bank-swizzle (rule #21 both-sides involution).
// - Bijective XCD swizzle (m204) for A-panel L2 reuse per XCD.
// - SPLITK: partial (fp32 Cf / bf16 Cb) at +z*M*N into DEDICATED buffers.
// ---------------------------------------------------------------------------
#define GSTAGE(bufsel, kk0)                                           \
  _Pragma("unroll") for (int si = 0; si < 4; ++si) {                  \
    const int s = wid + si * 4;                                       \
    gload16(A + (size_t)(m0 + s * 8 + srow) * ldk + (kk0) + skk,      \
            &lA[(bufsel) * 8192 + s * 512]);                          \
    gload16(BT + (size_t)(n0 + s * 8 + srow) * ldk + (kk0) + skk,     \
            &lB[(bufsel) * 8192 + s * 512]);                          \
  }

template <int EPI, int OUTBF, int SPLITK>
__global__ __launch_bounds__(256) void gemm_mfma(const short* __restrict__ A,
                                                 const short* __restrict__ BT,
                                                 const float* __restrict__ bias,
                                                 float* __restrict__ Cf,
                                                 __hip_bfloat16* __restrict__ Cb,
                                                 int M, int N, int ldk) {
  __shared__ short lA[2 * 128 * 64];
  __shared__ short lB[2 * 128 * 64];
  const int tid = threadIdx.x;
  const int wid = tid >> 6, lane = tid & 63;

  // XCD-aware bijective block swizzle (grids here always have nwg % 8 == 0)
  const int nwg = gridDim.x * gridDim.y;
  const int wg = blockIdx.y * gridDim.x + blockIdx.x;
  const int qq = nwg >> 3, rr = nwg & 7;
  const int xcd = wg & 7, idx = wg >> 3;
  const int wg2 = (xcd < rr ? xcd * (qq + 1) : rr * (qq + 1) + (xcd - rr) * qq) + idx;
  const int bx = wg2 % gridDim.x, by = wg2 / gridDim.x;

  const int m0 = by * 128, n0 = bx * 128;
  const int wm = (wid >> 1) * 64, wn = (wid & 1) * 64;
  const int srow = lane >> 3;                         // row within 8-row slab
  const int skk = (((lane & 7) ^ (lane >> 3)) << 3);  // swizzled k offset (elems)

  int kstart = 0, klen = ldk;
  if (SPLITK > 1) {
    klen = ldk / SPLITK;
    kstart = blockIdx.z * klen;
    if (OUTBF)
      Cb += (size_t)blockIdx.z * M * N;
    else
      Cf += (size_t)blockIdx.z * M * N;
  }
  const int kend = kstart + klen;

  f32x4 acc[4][4] = {};

  GSTAGE(0, kstart);  // prologue: 8 loads/wave in flight
  int cur = 0;
  for (int k0 = kstart; k0 < kend; k0 += 64) {
    if (k0 + 64 < kend) {
      GSTAGE(cur ^ 1, k0 + 64);                         // 16 in flight
      asm volatile("s_waitcnt vmcnt(8)" ::: "memory");  // oldest 8 (cur buf) done
    } else {
      asm volatile("s_waitcnt vmcnt(0)" ::: "memory");
    }
    asm volatile("s_barrier" ::: "memory");
    const short* bA = &lA[cur * 8192];
    const short* bB = &lB[cur * 8192];
#pragma unroll
    for (int kk = 0; kk < 2; ++kk) {
      const int krd = kk * 32 + (lane >> 4) * 8;
      const int rsel = lane & 15;
      const int kswz = krd ^ ((rsel & 7) << 3);  // same involution as store side
      bf16x8 af[4], bfr[4];
#pragma unroll
      for (int i = 0; i < 4; ++i) {
        af[i] = *(const bf16x8*)&bA[(wm + i * 16 + rsel) * 64 + kswz];
        bfr[i] = *(const bf16x8*)&bB[(wn + i * 16 + rsel) * 64 + kswz];
      }
#pragma unroll
      for (int i = 0; i < 4; ++i)
#pragma unroll
        for (int j = 0; j < 4; ++j)
          acc[i][j] = __builtin_amdgcn_mfma_f32_16x16x32_bf16(af[i], bfr[j], acc[i][j], 0, 0, 0);
    }
    // race fix: pin MFMA cluster, retire ALL LDS reads before signaling the
    // buffer reusable. vmcnt prefetch stays in flight (the dbuf win).
    __builtin_amdgcn_sched_barrier(0);
    asm volatile("s_waitcnt lgkmcnt(0)" ::: "memory");
    asm volatile("s_barrier" ::: "memory");
    cur ^= 1;
  }

  const int crow = (lane >> 4) * 4;
  const int ccol = lane & 15;
#pragma unroll
  for (int j = 0; j < 4; ++j) {
    const int col = n0 + wn + j * 16 + ccol;
    const float bv = bias ? bias[col] : 0.f;
#pragma unroll
    for (int i = 0; i < 4; ++i) {
#pragma unroll
      for (int r = 0; r < 4; ++r) {
        float v = acc[i][j][r] + bv;
        const int row = m0 + wm + i * 16 + crow + r;
        if (EPI == EPI_QKV) {
          const float vv = (col < 2048) ? fmaxf(v, 0.f) : v;
          Cb[(size_t)row * QS + col] = __float2bfloat16(vv);
        } else {
          if (EPI == EPI_RELU) v = fmaxf(v, 0.f);
          const size_t off = (size_t)row * N + col;
          if (OUTBF)
            Cb[off] = __float2bfloat16(v);
          else
            Cf[off] = v;
        }
      }
    }
  }
}

// ---------------------------------------------------------------------------
// 32x32 transpose-cast tile helper: W[K,N] f32 -> WT[N,K] bf16.
// ---------------------------------------------------------------------------
__device__ __forceinline__ void tc_tile(float (*tile)[33], const float* __restrict__ W,
                                        __hip_bfloat16* __restrict__ WT, int K, int N,
                                        int tlocal) {
  const int tilesN = N / 32;
  const int bk = (tlocal / tilesN) * 32, bn = (tlocal % tilesN) * 32;
  const int tx = threadIdx.x & 31, ty = threadIdx.x >> 5;  // 32x8
#pragma unroll
  for (int r = 0; r < 32; r += 8) tile[ty + r][tx] = W[(size_t)(bk + ty + r) * N + bn + tx];
  __syncthreads();
#pragma unroll
  for (int r = 0; r < 32; r += 8)
    WT[(size_t)(bn + ty + r) * K + bk + tx] = __float2bfloat16(tile[tx][ty + r]);
}

// ---------------------------------------------------------------------------
// Head kernel: W_amp / W_phi transpose-cast + x f32->bf16 cast.
// ---------------------------------------------------------------------------
__global__ __launch_bounds__(256) void tc_first(const float* __restrict__ W_amp,
                                                const float* __restrict__ W_phi,
                                                __hip_bfloat16* __restrict__ WTamp,
                                                __hip_bfloat16* __restrict__ WTphi,
                                                const float* __restrict__ x,
                                                __hip_bfloat16* __restrict__ xb) {
  __shared__ float tile[32][33];
  const int bid = blockIdx.x;
  if (bid >= 512) {
    const int i = ((bid - 512) * 256 + threadIdx.x) * 4;
    const float4 v = *(const float4*)&x[i];
    xb[i + 0] = __float2bfloat16(v.x);
    xb[i + 1] = __float2bfloat16(v.y);
    xb[i + 2] = __float2bfloat16(v.z);
    xb[i + 3] = __float2bfloat16(v.w);
    return;
  }
  if (bid < 256)
    tc_tile(tile, W_amp, WTamp, 1024, 256, bid);
  else
    tc_tile(tile, W_phi, WTphi, 1024, 256, bid - 256);
}

// ---------------------------------------------------------------------------
// amp/phi split-K reduce (4 bf16 partials) fused with activations and
// polar->cartesian. part layout: [4][M][512] bf16 (cols 0..255 amp, rest phi).
// ---------------------------------------------------------------------------
__global__ __launch_bounds__(256) void reduce_polar(const __hip_bfloat16* __restrict__ part,
                                                    const float* __restrict__ b_amp,
                                                    const float* __restrict__ b_phi,
                                                    __hip_bfloat16* __restrict__ outr,
                                                    __hip_bfloat16* __restrict__ outi) {
  const int idx = blockIdx.x * 256 + threadIdx.x;  // [0, M*NF)
  const int row = idx >> 8, c = idx & 255;
  const size_t MN = (size_t)Mm * 512;
  const size_t pa = (size_t)row * 512 + c;
  const unsigned short* pu = (const unsigned short*)part;
  float a = bf2f(pu[pa]) + bf2f(pu[pa + MN]) + bf2f(pu[pa + 2 * MN]) + bf2f(pu[pa + 3 * MN]) +
            b_amp[c];
  float ph = bf2f(pu[pa + 256]) + bf2f(pu[pa + 256 + MN]) + bf2f(pu[pa + 256 + 2 * MN]) +
             bf2f(pu[pa + 256 + 3 * MN]) + b_phi[c];
  a = (a > 0.f) ? (a + log1pf(expf(-a))) : log1pf(expf(a));
  ph = M_PI_F * tanhf(ph);
  float s, co;
  sincosf(ph, &s, &co);
  outr[idx] = __float2bfloat16(a * co);
  outi[idx] = __float2bfloat16(a * s);
}

// ---------------------------------------------------------------------------
// FUSED: resonator scan (blocks 0..63) || transpose-cast of the 6 remaining
// weights (blocks 64..12095) — independent work backfills the machine (r11).
// Scan: TIME-CHUNK PARALLEL (r6): contraction >= sigmoid(2.0)=0.881/step
// makes a 128-step warm-up from X=0 exact below bf16 quantization.
// ---------------------------------------------------------------------------
static constexpr int RES_P = 16;
static constexpr int RES_TC = 128;  // chunk length
static constexpr int RES_W = 128;   // warm-up length

#define RES_LOAD(buf_r, buf_i, tg)                                        \
  if ((tg) < cend) {                                                      \
    _Pragma("unroll") for (int i = 0; i < RES_P; ++i) {                   \
      buf_r[i] = __bfloat162float(ur[bbase + (size_t)((tg) + i) * NFf]);  \
      buf_i[i] = __bfloat162float(ui[bbase + (size_t)((tg) + i) * NFf]);  \
    }                                                                     \
  }

#define RES_STEP(buf_r, buf_i, tg)                                      \
  {                                                                      \
    const bool wr_ = (tg) >= cstart;                                     \
    _Pragma("unroll") for (int i = 0; i < RES_P; ++i) {                  \
      const float pr = fmaf(ar, Xr, fmaf(-ai, Xi, buf_r[i]));            \
      const float pim = fmaf(ar, Xi, fmaf(ai, Xr, buf_i[i]));            \
      const float mag = __builtin_amdgcn_sqrtf(fmaf(pr, pr, pim * pim)); \
      const float g = __builtin_amdgcn_rcpf(1.f + __expf(th - mag));     \
      Xr = pr * g;                                                       \
      Xi = pim * g;                                                      \
      if (wr_) {                                                         \
        const size_t fb = ((size_t)b * Tt + (tg) + i) * (3 * NFf);       \
        featb[fb + f] = __float2bfloat16(Xr);                            \
        featb[fb + NFf + f] = __float2bfloat16(Xi);                      \
        featb[fb + 2 * NFf + f] = __float2bfloat16(mag * g);             \
      }                                                                  \
    }                                                                    \
  }

struct STDesc {
  const float* src[6];
  __hip_bfloat16* dst[6];
  const __hip_bfloat16* ur;
  const __hip_bfloat16* ui;
  const float* omega;
  const float* ret_logit;
  const float* theta;
  __hip_bfloat16* featb;
};

__global__ __launch_bounds__(256) void scan_and_tc(STDesc d) {
  __shared__ float tile[32][33];
  const int bid = blockIdx.x;
  if (bid < 64) {
    if (threadIdx.x >= 64) return;  // scan uses 64 lanes; no barriers below
    const int tc = bid & 7;
    const int fs = (bid >> 3) & 3;
    const int b = bid >> 5;
    const int f = fs * 64 + threadIdx.x;
    const int cstart = tc * RES_TC;
    const int cend = cstart + RES_TC;
    const int tbeg = (cstart >= RES_W) ? cstart - RES_W : 0;
    const __hip_bfloat16* ur = d.ur;
    const __hip_bfloat16* ui = d.ui;
    __hip_bfloat16* featb = d.featb;
    const float dec = 1.f / (1.f + __expf(-d.ret_logit[f]));
    float so, co;
    sincosf(d.omega[f], &so, &co);
    const float ar = dec * co, ai = dec * so;
    const float th = d.theta[f];
    const size_t bbase = (size_t)b * Tt * NFf + f;
    float Xr = 0.f, Xi = 0.f;
    float Ar[RES_P], Ai[RES_P], Br[RES_P], Bi[RES_P];
    RES_LOAD(Ar, Ai, tbeg);
    for (int t0 = tbeg; t0 < cend; t0 += 2 * RES_P) {
      RES_LOAD(Br, Bi, t0 + RES_P);
      RES_STEP(Ar, Ai, t0);
      RES_LOAD(Ar, Ai, t0 + 2 * RES_P);
      RES_STEP(Br, Bi, t0 + RES_P);
    }
    return;
  }
  // transpose-cast region: W_feat, Wq, Wk, Wv, W1, W2
  constexpr int KS[6] = {768, 1024, 1024, 1024, 1024, 4096};
  constexpr int NS[6] = {1024, 1024, 1024, 1024, 4096, 1024};
  constexpr int CUM[7] = {0, 768, 1792, 2816, 3840, 7936, 12032};
  const int t = bid - 64;
  int w = 0;
#pragma unroll
  for (int i = 0; i < 6; ++i)
    if (t >= CUM[i + 1]) w = i + 1;
  tc_tile(tile, d.src[w], d.dst[w], KS[w], NS[w], t - CUM[w]);
}

// ---------------------------------------------------------------------------
// Attention phase A — MFMA (r22): S[d][e] = sum_s K[s][d]*V[s][e] per chunk.
// Stage K^T[d][s] and V^T[e][s] in LDS (same transposed-staging idiom as
// attn_out); first MFMA operand maps C-rows (d), second maps C-cols (e) —
// the twice-verified gemm_mfma convention. 8 MFMAs/wave replace ~1024
// VALU fma/thread. fp32 S out (r21 precision), fp32 Ksum by wave 0.
// ---------------------------------------------------------------------------
__global__ __launch_bounds__(256) void attn_chunk_kv(const __hip_bfloat16* __restrict__ k,
                                                     const __hip_bfloat16* __restrict__ v,
                                                     float* __restrict__ S,
                                                     float* __restrict__ Ksum) {
  __shared__ unsigned short Kt[64][72];  // K^T [d][s] bf16
  __shared__ unsigned short Vt[64][72];  // V^T [e][s] bf16
  const int g = blockIdx.x;
  const int j = g & (NCHK - 1), bh = g >> 4;
  const int b = bh >> 4, h = bh & (Hh - 1);
  const int tid = threadIdx.x;
  const size_t rowbase = (size_t)(b * Tt + j * CHK) * QS + h * DHh;
  const unsigned short* ku = (const unsigned short*)k;
  const unsigned short* vu = (const unsigned short*)v;
  for (int l = tid; l < 4096; l += 256) {
    const int s = l >> 6, d = l & 63;
    Kt[d][s] = ku[rowbase + (size_t)s * QS + d];
    Vt[d][s] = vu[rowbase + (size_t)s * QS + d];
  }
  __syncthreads();
  // Ksum: wave 0 threads sum K^T rows (LDS reads only; no barrier needed)
  if (tid < 64) {
    float ks = 0.f;
#pragma unroll
    for (int s = 0; s < 64; ++s) ks += bf2f(Kt[tid][s]);
    Ksum[(size_t)g * 64 + tid] = ks;
  }
  // MFMA: wave w owns C rows [16w,16w+16)
  const int w = tid >> 6, ln = tid & 63;
  const int fr = ln & 15;  // A-row / B-col within a 16-tile
  const int kh = ln >> 4;  // k-subgroup (s-elements kh*8.. and +32)
  const bf16x8 a0 = *(const bf16x8*)&Kt[w * 16 + fr][kh * 8];
  const bf16x8 a1 = *(const bf16x8*)&Kt[w * 16 + fr][kh * 8 + 32];
  f32x4 acc[4] = {};
#pragma unroll
  for (int ct = 0; ct < 4; ++ct) {
    const bf16x8 b0 = *(const bf16x8*)&Vt[ct * 16 + fr][kh * 8];
    const bf16x8 b1 = *(const bf16x8*)&Vt[ct * 16 + fr][kh * 8 + 32];
    acc[ct] = __builtin_amdgcn_mfma_f32_16x16x32_bf16(a0, b0, acc[ct], 0, 0, 0);
    acc[ct] = __builtin_amdgcn_mfma_f32_16x16x32_bf16(a1, b1, acc[ct], 0, 0, 0);
  }
  // C write: d = w*16 + kh*4 + r, e = ct*16 + fr
  float* Sg = S + (size_t)g * 4096;
#pragma unroll
  for (int r = 0; r < 4; ++r) {
    const int dd = w * 16 + kh * 4 + r;
#pragma unroll
    for (int ct = 0; ct < 4; ++ct) Sg[(size_t)dd * 64 + ct * 16 + fr] = acc[ct][r];
  }
}

// ---------------------------------------------------------------------------
// Attention phase B: EXCLUSIVE prefix over the 16 chunks per (b,h).
// FULLY PARALLEL (r10): one thread per chain; all fp32 (r21).
// ---------------------------------------------------------------------------
__global__ __launch_bounds__(256) void attn_prefix(float* __restrict__ S,
                                                   float* __restrict__ Ksum) {
  const int bid = blockIdx.x;
  const int tid = threadIdx.x;
  if (bid < 512) {
    const int bh = bid >> 4, r = bid & 15;
    const int de = r * 256 + tid;
    const size_t base = (size_t)bh * (NCHK * 4096) + de;
    float vv[NCHK];
#pragma unroll
    for (int j = 0; j < NCHK; ++j) vv[j] = S[base + (size_t)j * 4096];
    float run = 0.f;
#pragma unroll
    for (int j = 0; j < NCHK; ++j) {
      const float tmp = vv[j];
      S[base + (size_t)j * 4096] = run;
      run += tmp;
    }
  } else {
    const int cid = (bid - 512) * 256 + tid;  // [0, 2048)
    const int bh = cid >> 6, d = cid & 63;
    const size_t base = (size_t)bh * (NCHK * 64) + d;
    float vv[NCHK];
#pragma unroll
    for (int j = 0; j < NCHK; ++j) vv[j] = Ksum[base + (size_t)j * 64];
    float run = 0.f;
#pragma unroll
    for (int j = 0; j < NCHK; ++j) {
      const float tmp = vv[j];
      Ksum[base + (size_t)j * 64] = run;
      run += tmp;
    }
  }
}

// ---------------------------------------------------------------------------
// Attention phase C + fused per-head layernorm — FULLY MFMA.
// Stage 1 (QK^T): frags direct from global; masked scores stored as
// DOUBLE-BF16 (hi + lo) At[t][s] (r17).
// Stage 2: num[t][e] = At @ V + Q @ P via MFMA. r21: P fp32 in global,
// consumed as DOUBLE-BF16 (hi + lo). V staged transposed; 8 MFMAs per ct.
// Same operand convention as gemm_mfma. LN epilogue: row t spans 16
// consecutive lanes -> shfl_xor 1/2/4/8. All barriers are __syncthreads().
// ---------------------------------------------------------------------------
__global__ __launch_bounds__(256) void attn_out(const __hip_bfloat16* __restrict__ q,
                                                const __hip_bfloat16* __restrict__ k,
                                                const __hip_bfloat16* __restrict__ v,
                                                const float* __restrict__ S,
                                                const float* __restrict__ Ksum,
                                                const float* __restrict__ lnw,
                                                const float* __restrict__ lnb,
                                                __hip_bfloat16* __restrict__ yhb) {
  __shared__ unsigned short Atb[64][72];  // masked scores hi [t][s] bf16
  __shared__ unsigned short Atl[64][72];  // masked scores lo [t][s] bf16
  __shared__ unsigned short Vt[64][72];   // V^T [e][s] bf16
  __shared__ unsigned short Pth[64][72];  // P^T hi [e][d] bf16
  __shared__ unsigned short Ptl[64][72];  // P^T lo [e][d] bf16
  __shared__ float denp[4][64];
  __shared__ float dens[64];
  const int g = blockIdx.x;
  const int j = g & (NCHK - 1), bh = g >> 4;
  const int b = bh >> 4, h = bh & (Hh - 1);
  const int tid = threadIdx.x;
  const size_t rowbase = (size_t)(b * Tt + j * CHK) * QS + h * DHh;
  const unsigned short* qu = (const unsigned short*)q;
  const unsigned short* ku = (const unsigned short*)k;
  const unsigned short* vu = (const unsigned short*)v;
  const float* Pg = S + (size_t)g * 4096;

  // entry: stage V^T (bf16 copy) and P^T as hi/lo double-bf16 from fp32
  for (int l = tid; l < 4096; l += 256) {
    const int s = l >> 6, e = l & 63;
    Vt[e][s] = vu[rowbase + (size_t)s * QS + e];
    const float pv = Pg[l];  // l = d*64+e, d = l>>6 -> store Pt[e][d]
    const unsigned short ph = f2bf(pv);
    Pth[e][s] = ph;
    Ptl[e][s] = f2bf(pv - bf2f(ph));
  }
  // --- stage 1: QK^T via MFMA, fragments direct from global ---
  {
    const int w4 = tid >> 6, ln = tid & 63;
    const int fr = ln & 15;
    const int kh = ln >> 4;
    const unsigned short* kr = ku + rowbase + (size_t)(w4 * 16 + fr) * QS + kh * 8;
    const bf16x8 a0 = *(const bf16x8*)&kr[0];
    const bf16x8 a1 = *(const bf16x8*)&kr[32];
    f32x4 accQK[4] = {};
#pragma unroll
    for (int tt = 0; tt < 4; ++tt) {
      const unsigned short* qr = qu + rowbase + (size_t)(tt * 16 + fr) * QS + kh * 8;
      const bf16x8 b0 = *(const bf16x8*)&qr[0];
      const bf16x8 b1 = *(const bf16x8*)&qr[32];
      accQK[tt] = __builtin_amdgcn_mfma_f32_16x16x32_bf16(a0, b0, accQK[tt], 0, 0, 0);
      accQK[tt] = __builtin_amdgcn_mfma_f32_16x16x32_bf16(a1, b1, accQK[tt], 0, 0, 0);
    }
    // mask (keep s <= t), write hi/lo At[t][s], per-wave den partials
#pragma unroll
    for (int tt = 0; tt < 4; ++tt) {
      const int t = tt * 16 + fr;
      float dp = 0.f;
#pragma unroll
      for (int r = 0; r < 4; ++r) {
        const int s = w4 * 16 + kh * 4 + r;
        const float val = (s <= t) ? accQK[tt][r] : 0.f;
        const unsigned short hv = f2bf(val);
        Atb[t][s] = hv;
        Atl[t][s] = f2bf(val - bf2f(hv));
        dp += val;
      }
      dp += __shfl_xor(dp, 16);
      dp += __shfl_xor(dp, 32);
      if (ln < 16) denp[w4][t] = dp;
    }
  }
  __syncthreads();
  // --- den: qpk (q direct from global, sg-split) + denp sums ---
  {
    const int t = tid >> 2, sg = tid & 3;
    const float* pk = Ksum + (size_t)g * 64;
    const unsigned short* qr = qu + rowbase + (size_t)t * QS + sg * 16;
    float qpk = 0.f;
#pragma unroll
    for (int i = 0; i < 16; ++i) qpk = fmaf(bf2f(qr[i]), pk[sg * 16 + i], qpk);
    qpk += __shfl_xor(qpk, 1);
    qpk += __shfl_xor(qpk, 2);
    if (sg == 0)
      dens[t] = denp[0][t] + denp[1][t] + denp[2][t] + denp[3][t] + qpk + 1e-6f;
  }
  __syncthreads();
  // --- stage 2: num = At @ V + Q @ P via MFMA (hi+lo for At AND P) ---
  const int w = tid >> 6, ln = tid & 63;
  const int fr = ln & 15;
  const int kh = ln >> 4;
  const bf16x8 sa0 = *(const bf16x8*)&Atb[w * 16 + fr][kh * 8];
  const bf16x8 sa1 = *(const bf16x8*)&Atb[w * 16 + fr][kh * 8 + 32];
  const bf16x8 la0 = *(const bf16x8*)&Atl[w * 16 + fr][kh * 8];
  const bf16x8 la1 = *(const bf16x8*)&Atl[w * 16 + fr][kh * 8 + 32];
  const unsigned short* q2 = qu + rowbase + (size_t)(w * 16 + fr) * QS + kh * 8;
  const bf16x8 qa0 = *(const bf16x8*)&q2[0];
  const bf16x8 qa1 = *(const bf16x8*)&q2[32];
  f32x4 acc2[4] = {};
#pragma unroll
  for (int ct = 0; ct < 4; ++ct) {
    const bf16x8 vb0 = *(const bf16x8*)&Vt[ct * 16 + fr][kh * 8];
    const bf16x8 vb1 = *(const bf16x8*)&Vt[ct * 16 + fr][kh * 8 + 32];
    const bf16x8 ph0 = *(const bf16x8*)&Pth[ct * 16 + fr][kh * 8];
    const bf16x8 ph1 = *(const bf16x8*)&Pth[ct * 16 + fr][kh * 8 + 32];
    const bf16x8 pl0 = *(const bf16x8*)&Ptl[ct * 16 + fr][kh * 8];
    const bf16x8 pl1 = *(const bf16x8*)&Ptl[ct * 16 + fr][kh * 8 + 32];
    acc2[ct] = __builtin_amdgcn_mfma_f32_16x16x32_bf16(sa0, vb0, acc2[ct], 0, 0, 0);
    acc2[ct] = __builtin_amdgcn_mfma_f32_16x16x32_bf16(sa1, vb1, acc2[ct], 0, 0, 0);
    acc2[ct] = __builtin_amdgcn_mfma_f32_16x16x32_bf16(la0, vb0, acc2[ct], 0, 0, 0);
    acc2[ct] = __builtin_amdgcn_mfma_f32_16x16x32_bf16(la1, vb1, acc2[ct], 0, 0, 0);
    acc2[ct] = __builtin_amdgcn_mfma_f32_16x16x32_bf16(qa0, ph0, acc2[ct], 0, 0, 0);
    acc2[ct] = __builtin_amdgcn_mfma_f32_16x16x32_bf16(qa1, ph1, acc2[ct], 0, 0, 0);
    acc2[ct] = __builtin_amdgcn_mfma_f32_16x16x32_bf16(qa0, pl0, acc2[ct], 0, 0, 0);
    acc2[ct] = __builtin_amdgcn_mfma_f32_16x16x32_bf16(qa1, pl1, acc2[ct], 0, 0, 0);
  }
  // --- epilogue: divide by den, per-head LN (row t in 16 consecutive lanes) ---
  unsigned short* yb = (unsigned short*)yhb;
#pragma unroll
  for (int r = 0; r < 4; ++r) {
    const int t = w * 16 + kh * 4 + r;
    const float inv = 1.f / dens[t];
    float o[4];
    float s1 = 0.f, s2 = 0.f;
#pragma unroll
    for (int ct = 0; ct < 4; ++ct) {
      o[ct] = acc2[ct][r] * inv;
      s1 += o[ct];
      s2 += o[ct] * o[ct];
    }
#pragma unroll
    for (int m = 1; m < 16; m <<= 1) {
      s1 += __shfl_xor(s1, m);
      s2 += __shfl_xor(s2, m);
    }
    const float mean = s1 * (1.f / 64.f);
    const float var = s2 * (1.f / 64.f) - mean * mean;
    const float rsv = rsqrtf(var + 1e-5f);
    unsigned short* yg = yb + (size_t)(b * Tt + j * CHK + t) * Dd + h * DHh;
#pragma unroll
    for (int ct = 0; ct < 4; ++ct) {
      const int e = ct * 16 + fr;
      const float rr = (o[ct] - mean) * rsv * lnw[h * DHh + e] + lnb[h * DHh + e];
      yg[e] = f2bf(rr);
    }
  }
}

// ---------------------------------------------------------------------------
// Fused FFN2-reduce (4 bf16 split-K partials) + bias + relu + residual +
// final layernorm over D=1024.
// ---------------------------------------------------------------------------
__global__ __launch_bounds__(256) void final_ln(const float* __restrict__ x,
                                                const __hip_bfloat16* __restrict__ part,
                                                const float* __restrict__ b2,
                                                const float* __restrict__ w,
                                                const float* __restrict__ bb,
                                                float* __restrict__ out) {
  __shared__ float r1[4], r2[4];
  const int row = blockIdx.x;
  const int tid = threadIdx.x;
  const size_t off = (size_t)row * Dd + tid * 4;
  const size_t MN = (size_t)Mm * Dd;
  float acc4[4] = {0.f, 0.f, 0.f, 0.f};
#pragma unroll
  for (int z = 0; z < 4; ++z) {
    const ushort4 u = *(const ushort4*)&part[off + (size_t)z * MN];
    acc4[0] += bf2f(u.x);
    acc4[1] += bf2f(u.y);
    acc4[2] += bf2f(u.z);
    acc4[3] += bf2f(u.w);
  }
  const float4 bv = *(const float4*)&b2[tid * 4];
  const float4 xa = *(const float4*)&x[off];
  float z[4];
  z[0] = xa.x + fmaxf(acc4[0] + bv.x, 0.f);
  z[1] = xa.y + fmaxf(acc4[1] + bv.y, 0.f);
  z[2] = xa.z + fmaxf(acc4[2] + bv.z, 0.f);
  z[3] = xa.w + fmaxf(acc4[3] + bv.w, 0.f);
  float s1 = z[0] + z[1] + z[2] + z[3];
  float s2 = z[0] * z[0] + z[1] * z[1] + z[2] * z[2] + z[3] * z[3];
#pragma unroll
  for (int o = 1; o < 64; o <<= 1) {
    s1 += __shfl_xor(s1, o);
    s2 += __shfl_xor(s2, o);
  }
  const int wid = tid >> 6;
  if ((tid & 63) == 0) {
    r1[wid] = s1;
    r2[wid] = s2;
  }
  __syncthreads();
  const float t1 = r1[0] + r1[1] + r1[2] + r1[3];
  const float t2 = r2[0] + r2[1] + r2[2] + r2[3];
  const float mu = t1 * (1.f / Dd);
  const float var = t2 * (1.f / Dd) - mu * mu;
  const float rsv = rsqrtf(var + 1e-5f);
  float4 o4;
  float* op = &o4.x;
#pragma unroll
  for (int jj = 0; jj < 4; ++jj) op[jj] = (z[jj] - mu) * rsv * w[tid * 4 + jj] + bb[tid * 4 + jj];
  *(float4*)&out[off] = o4;
}

// ---------------------------------------------------------------------------
extern "C" void kernel_launch(void* const* d_in, const int* in_sizes, int n_in,
                              void* d_out, int out_size, void* d_ws, size_t ws_size,
                              hipStream_t stream) {
  const float* x = (const float*)d_in[0];
  const float* W_amp = (const float*)d_in[1];
  const float* b_amp = (const float*)d_in[2];
  const float* W_phi = (const float*)d_in[3];
  const float* b_phi = (const float*)d_in[4];
  const float* omega = (const float*)d_in[5];
  const float* ret_logit = (const float*)d_in[6];
  const float* theta = (const float*)d_in[7];
  const float* W_feat = (const float*)d_in[8];
  const float* b_feat = (const float*)d_in[9];
  const float* Wq = (const float*)d_in[10];
  const float* Wk = (const float*)d_in[11];
  const float* Wv = (const float*)d_in[12];
  const float* lnh_w = (const float*)d_in[13];
  const float* lnh_b = (const float*)d_in[14];
  const float* W1 = (const float*)d_in[15];
  const float* b1 = (const float*)d_in[16];
  const float* W2 = (const float*)d_in[17];
  const float* b2 = (const float*)d_in[18];
  const float* ln_w = (const float*)d_in[19];
  const float* ln_b = (const float*)d_in[20];

  // ---- workspace bump allocator (256B aligned); dedicated buffers ----
  char* p = (char*)d_ws;
  auto alloc = [&](size_t bytes) {
    char* r = p;
    p += (bytes + 255) & ~(size_t)255;
    return r;
  };
  __hip_bfloat16* xb = (__hip_bfloat16*)alloc((size_t)Mm * Dd * 2);   // later: featb
  __hip_bfloat16* urh = (__hip_bfloat16*)alloc((size_t)Mm * NFf * 2);
  __hip_bfloat16* uih = (__hip_bfloat16*)alloc((size_t)Mm * NFf * 2);
  __hip_bfloat16* WTamp = (__hip_bfloat16*)alloc((size_t)NFf * Dd * 2);  // +WTphi contiguous
  __hip_bfloat16* WTphi = (__hip_bfloat16*)alloc((size_t)NFf * Dd * 2);
  __hip_bfloat16* WTfeat = (__hip_bfloat16*)alloc((size_t)Dd * 3 * NFf * 2);
  __hip_bfloat16* WTq = (__hip_bfloat16*)alloc((size_t)Dd * Dd * 2);  // +k+v contiguous
  __hip_bfloat16* WTk = (__hip_bfloat16*)alloc((size_t)Dd * Dd * 2);
  __hip_bfloat16* WTv = (__hip_bfloat16*)alloc((size_t)Dd * Dd * 2);
  __hip_bfloat16* WT1 = (__hip_bfloat16*)alloc((size_t)Rr * Dd * 2);
  __hip_bfloat16* WT2 = (__hip_bfloat16*)alloc((size_t)Dd * Rr * 2);
  __hip_bfloat16* hb = (__hip_bfloat16*)alloc((size_t)Mm * Dd * 2);
  __hip_bfloat16* qkvb = (__hip_bfloat16*)alloc((size_t)Mm * QS * 2);  // 12 MB
  __hip_bfloat16* yhb = (__hip_bfloat16*)alloc((size_t)Mm * Dd * 2);   // 4 MB
  float* S = (float*)alloc((size_t)Bb * Hh * NCHK * 4096 * 4);         // 8 MB fp32 (r21)
  float* Ksum = (float*)alloc((size_t)Bb * Hh * NCHK * 64 * 4);
  __hip_bfloat16* f1b = (__hip_bfloat16*)alloc((size_t)Mm * Rr * 2);   // 16 MB
  __hip_bfloat16* pamp = (__hip_bfloat16*)alloc((size_t)4 * Mm * 512 * 2);   // 8 MB dedicated
  __hip_bfloat16* pffn2 = (__hip_bfloat16*)alloc((size_t)4 * Mm * Dd * 2);   // 16 MB dedicated

  __hip_bfloat16* featb = xb;  // xb dead after ampphi GEMM (stream-ordered)
  const __hip_bfloat16* q = qkvb;
  const __hip_bfloat16* k = qkvb + 1024;
  const __hip_bfloat16* v = qkvb + 2048;
  float* out = (float*)d_out;

  const dim3 blk(256);

  // 0: amp/phi weight transposes + x cast (what the first GEMM needs)
  tc_first<<<dim3(2560), blk, 0, stream>>>(W_amp, W_phi, WTamp, WTphi, x, xb);

  // 1: fused amp/phi projection, split-K=4 (256 blocks, bf16 partials), then
  //    fused reduce + softplus/tanh + polar -> bf16 u
  gemm_mfma<EPI_NONE, 1, 4><<<dim3(512 / 128, Mm / 128, 4), blk, 0, stream>>>(
      (const short*)xb, (const short*)WTamp, nullptr, nullptr, pamp, Mm, 512, Dd);
  reduce_polar<<<dim3(Mm * NFf / 256), blk, 0, stream>>>(pamp, b_amp, b_phi, urh, uih);

  // 2: FUSED resonator scan (64 blocks) || remaining weight transposes
  STDesc st;
  st.src[0] = W_feat; st.dst[0] = WTfeat;
  st.src[1] = Wq; st.dst[1] = WTq;
  st.src[2] = Wk; st.dst[2] = WTk;
  st.src[3] = Wv; st.dst[3] = WTv;
  st.src[4] = W1; st.dst[4] = WT1;
  st.src[5] = W2; st.dst[5] = WT2;
  st.ur = urh; st.ui = uih;
  st.omega = omega; st.ret_logit = ret_logit; st.theta = theta;
  st.featb = featb;
  scan_and_tc<<<dim3(64 + 12032), blk, 0, stream>>>(st);

  // 3: feat projection -> h (bf16)
  gemm_mfma<EPI_RELU, 1, 0><<<dim3(Dd / 128, Mm / 128), blk, 0, stream>>>(
      (const short*)featb, (const short*)WTfeat, b_feat, nullptr, hb, Mm, Dd, 3 * NFf);

  // 4: fused q,k,v projection -> bf16 qkvb (384 blocks)
  gemm_mfma<EPI_QKV, 1, 0><<<dim3(QS / 128, Mm / 128), blk, 0, stream>>>(
      (const short*)hb, (const short*)WTq, nullptr, nullptr, qkvb, Mm, QS, Dd);

  // 5: chunked causal linear attention (+ fused per-head LN in attn_out)
  attn_chunk_kv<<<dim3(Bb * Hh * NCHK), blk, 0, stream>>>(k, v, S, Ksum);
  attn_prefix<<<dim3(520), blk, 0, stream>>>(S, Ksum);
  attn_out<<<dim3(Bb * Hh * NCHK), blk, 0, stream>>>(q, k, v, S, Ksum, lnh_w, lnh_b, yhb);

  // 6: FFN1 -> f1b (bf16); 512 blocks = 2 blocks/CU (dbuf LDS cap)
  gemm_mfma<EPI_RELU, 1, 0><<<dim3(Rr / 128, Mm / 128), blk, 0, stream>>>(
      (const short*)yhb, (const short*)WT1, b1, nullptr, f1b, Mm, Rr, Dd);

  // 7: FFN2 split-K=4, bf16 partials -> pffn2; 512 blocks = 2 blocks/CU
  gemm_mfma<EPI_NONE, 1, 4><<<dim3(Dd / 128, Mm / 128, 4), blk, 0, stream>>>(
      (const short*)f1b, (const short*)WT2, nullptr, nullptr, pffn2, Mm, Dd, Rr);

  // 8: fused reduce(4x bf16) + bias + relu + residual + final layernorm
  final_ln<<<dim3(Mm), blk, 0, stream>>>(x, pffn2, b2, ln_w, ln_b, out);
}

// Round 23
// 158.764 us; speedup vs baseline: 1.0349x; 1.0027x over previous
//
#include <hip/hip_runtime.h>
#include <hip/hip_bf16.h>
#include <math.h>

#ifndef M_PI_F
#define M_PI_F 3.14159265358979323846f
#endif

static constexpr int Bb = 2, Tt = 1024, Dd = 1024, Hh = 16, DHh = 64, NFf = 256, Rr = 4096;
static constexpr int Mm = Bb * Tt;
static constexpr int CHK = 64, NCHK = Tt / CHK;  // attention chunking
static constexpr int QS = 3072;                  // fused qkv row stride

enum Epi { EPI_NONE = 0, EPI_RELU, EPI_QKV };

typedef __attribute__((ext_vector_type(8))) short bf16x8;
typedef __attribute__((ext_vector_type(4))) float f32x4;

__device__ inline float bf2f(unsigned short u) {
  union { unsigned int i; float f; } c;
  c.i = (unsigned int)u << 16;
  return c.f;
}

__device__ inline unsigned short f2bf(float f) {
  __hip_bfloat16 h = __float2bfloat16(f);
  return *(unsigned short*)&h;
}

// ---------------------------------------------------------------------------
// async global->LDS, 16B per lane. LDS dest is wave-uniform base; HW adds
// lane*16. Global address is per-lane.
// ---------------------------------------------------------------------------
__device__ inline void gload16(const short* g, short* l) {
  __builtin_amdgcn_global_load_lds(
      (const __attribute__((address_space(1))) unsigned int*)g,
      (__attribute__((address_space(3))) unsigned int*)l, 16, 0, 0);
}

// ---------------------------------------------------------------------------
// bf16 MFMA GEMM: C[M,N] = epi(A[M,K] @ BT[N,K]^T + bias)
// 128x128 tile, BK=64, 4 waves (2x2), each 64x64 via 4x4 frags of 16x16x32.
// - Double-buffered K-loop with counted vmcnt (r7). r18 A/B: single-buffer
//   at 4 blocks/CU REGRESSED — counted prefetch off the critical path beats
//   extra co-residency beyond 2 blocks/CU.
// - r20 RACE FIX (kept): sched_barrier(0) + s_waitcnt lgkmcnt(0) before the
//   done-reading s_barrier. s_barrier does NOT wait for outstanding LDS ops
//   and hipcc can sink register-only MFMAs past asm barriers (rule #18);
//   without the drain a wave could cross with ds_reads in flight while the
//   next-iteration global_load_lds overwrites the buffer (r17-r19 wobble).
// - LDS XOR bank-swizzle (rule #21 both-sides involution).
// - Bijective XCD swizzle (m204) for A-panel L2 reuse per XCD.
// - SPLITK: partial (fp32 Cf / bf16 Cb) at +z*M*N into DEDICATED buffers.
// ---------------------------------------------------------------------------
#define GSTAGE(bufsel, kk0)                                           \
  _Pragma("unroll") for (int si = 0; si < 4; ++si) {                  \
    const int s = wid + si * 4;                                       \
    gload16(A + (size_t)(m0 + s * 8 + srow) * ldk + (kk0) + skk,      \
            &lA[(bufsel) * 8192 + s * 512]);                          \
    gload16(BT + (size_t)(n0 + s * 8 + srow) * ldk + (kk0) + skk,     \
            &lB[(bufsel) * 8192 + s * 512]);                          \
  }

template <int EPI, int OUTBF, int SPLITK>
__global__ __launch_bounds__(256) void gemm_mfma(const short* __restrict__ A,
                                                 const short* __restrict__ BT,
                                                 const float* __restrict__ bias,
                                                 float* __restrict__ Cf,
                                                 __hip_bfloat16* __restrict__ Cb,
                                                 int M, int N, int ldk) {
  __shared__ short lA[2 * 128 * 64];
  __shared__ short lB[2 * 128 * 64];
  const int tid = threadIdx.x;
  const int wid = tid >> 6, lane = tid & 63;

  // XCD-aware bijective block swizzle (grids here always have nwg % 8 == 0)
  const int nwg = gridDim.x * gridDim.y;
  const int wg = blockIdx.y * gridDim.x + blockIdx.x;
  const int qq = nwg >> 3, rr = nwg & 7;
  const int xcd = wg & 7, idx = wg >> 3;
  const int wg2 = (xcd < rr ? xcd * (qq + 1) : rr * (qq + 1) + (xcd - rr) * qq) + idx;
  const int bx = wg2 % gridDim.x, by = wg2 / gridDim.x;

  const int m0 = by * 128, n0 = bx * 128;
  const int wm = (wid >> 1) * 64, wn = (wid & 1) * 64;
  const int srow = lane >> 3;                         // row within 8-row slab
  const int skk = (((lane & 7) ^ (lane >> 3)) << 3);  // swizzled k offset (elems)

  int kstart = 0, klen = ldk;
  if (SPLITK > 1) {
    klen = ldk / SPLITK;
    kstart = blockIdx.z * klen;
    if (OUTBF)
      Cb += (size_t)blockIdx.z * M * N;
    else
      Cf += (size_t)blockIdx.z * M * N;
  }
  const int kend = kstart + klen;

  f32x4 acc[4][4] = {};

  GSTAGE(0, kstart);  // prologue: 8 loads/wave in flight
  int cur = 0;
  for (int k0 = kstart; k0 < kend; k0 += 64) {
    if (k0 + 64 < kend) {
      GSTAGE(cur ^ 1, k0 + 64);                         // 16 in flight
      asm volatile("s_waitcnt vmcnt(8)" ::: "memory");  // oldest 8 (cur buf) done
    } else {
      asm volatile("s_waitcnt vmcnt(0)" ::: "memory");
    }
    asm volatile("s_barrier" ::: "memory");
    const short* bA = &lA[cur * 8192];
    const short* bB = &lB[cur * 8192];
#pragma unroll
    for (int kk = 0; kk < 2; ++kk) {
      const int krd = kk * 32 + (lane >> 4) * 8;
      const int rsel = lane & 15;
      const int kswz = krd ^ ((rsel & 7) << 3);  // same involution as store side
      bf16x8 af[4], bfr[4];
#pragma unroll
      for (int i = 0; i < 4; ++i) {
        af[i] = *(const bf16x8*)&bA[(wm + i * 16 + rsel) * 64 + kswz];
        bfr[i] = *(const bf16x8*)&bB[(wn + i * 16 + rsel) * 64 + kswz];
      }
#pragma unroll
      for (int i = 0; i < 4; ++i)
#pragma unroll
        for (int j = 0; j < 4; ++j)
          acc[i][j] = __builtin_amdgcn_mfma_f32_16x16x32_bf16(af[i], bfr[j], acc[i][j], 0, 0, 0);
    }
    // race fix: pin MFMA cluster, retire ALL LDS reads before signaling the
    // buffer reusable. vmcnt prefetch stays in flight (the dbuf win).
    __builtin_amdgcn_sched_barrier(0);
    asm volatile("s_waitcnt lgkmcnt(0)" ::: "memory");
    asm volatile("s_barrier" ::: "memory");
    cur ^= 1;
  }

  const int crow = (lane >> 4) * 4;
  const int ccol = lane & 15;
#pragma unroll
  for (int j = 0; j < 4; ++j) {
    const int col = n0 + wn + j * 16 + ccol;
    const float bv = bias ? bias[col] : 0.f;
#pragma unroll
    for (int i = 0; i < 4; ++i) {
#pragma unroll
      for (int r = 0; r < 4; ++r) {
        float v = acc[i][j][r] + bv;
        const int row = m0 + wm + i * 16 + crow + r;
        if (EPI == EPI_QKV) {
          const float vv = (col < 2048) ? fmaxf(v, 0.f) : v;
          Cb[(size_t)row * QS + col] = __float2bfloat16(vv);
        } else {
          if (EPI == EPI_RELU) v = fmaxf(v, 0.f);
          const size_t off = (size_t)row * N + col;
          if (OUTBF)
            Cb[off] = __float2bfloat16(v);
          else
            Cf[off] = v;
        }
      }
    }
  }
}

// ---------------------------------------------------------------------------
// 32x32 transpose-cast tile helper: W[K,N] f32 -> WT[N,K] bf16.
// ---------------------------------------------------------------------------
__device__ __forceinline__ void tc_tile(float (*tile)[33], const float* __restrict__ W,
                                        __hip_bfloat16* __restrict__ WT, int K, int N,
                                        int tlocal) {
  const int tilesN = N / 32;
  const int bk = (tlocal / tilesN) * 32, bn = (tlocal % tilesN) * 32;
  const int tx = threadIdx.x & 31, ty = threadIdx.x >> 5;  // 32x8
#pragma unroll
  for (int r = 0; r < 32; r += 8) tile[ty + r][tx] = W[(size_t)(bk + ty + r) * N + bn + tx];
  __syncthreads();
#pragma unroll
  for (int r = 0; r < 32; r += 8)
    WT[(size_t)(bn + ty + r) * K + bk + tx] = __float2bfloat16(tile[tx][ty + r]);
}

// ---------------------------------------------------------------------------
// Head kernel: W_amp / W_phi transpose-cast + x f32->bf16 cast.
// ---------------------------------------------------------------------------
__global__ __launch_bounds__(256) void tc_first(const float* __restrict__ W_amp,
                                                const float* __restrict__ W_phi,
                                                __hip_bfloat16* __restrict__ WTamp,
                                                __hip_bfloat16* __restrict__ WTphi,
                                                const float* __restrict__ x,
                                                __hip_bfloat16* __restrict__ xb) {
  __shared__ float tile[32][33];
  const int bid = blockIdx.x;
  if (bid >= 512) {
    const int i = ((bid - 512) * 256 + threadIdx.x) * 4;
    const float4 v = *(const float4*)&x[i];
    xb[i + 0] = __float2bfloat16(v.x);
    xb[i + 1] = __float2bfloat16(v.y);
    xb[i + 2] = __float2bfloat16(v.z);
    xb[i + 3] = __float2bfloat16(v.w);
    return;
  }
  if (bid < 256)
    tc_tile(tile, W_amp, WTamp, 1024, 256, bid);
  else
    tc_tile(tile, W_phi, WTphi, 1024, 256, bid - 256);
}

// ---------------------------------------------------------------------------
// amp/phi split-K reduce (4 bf16 partials) fused with activations and
// polar->cartesian. part layout: [4][M][512] bf16 (cols 0..255 amp, rest phi).
// ---------------------------------------------------------------------------
__global__ __launch_bounds__(256) void reduce_polar(const __hip_bfloat16* __restrict__ part,
                                                    const float* __restrict__ b_amp,
                                                    const float* __restrict__ b_phi,
                                                    __hip_bfloat16* __restrict__ outr,
                                                    __hip_bfloat16* __restrict__ outi) {
  const int idx = blockIdx.x * 256 + threadIdx.x;  // [0, M*NF)
  const int row = idx >> 8, c = idx & 255;
  const size_t MN = (size_t)Mm * 512;
  const size_t pa = (size_t)row * 512 + c;
  const unsigned short* pu = (const unsigned short*)part;
  float a = bf2f(pu[pa]) + bf2f(pu[pa + MN]) + bf2f(pu[pa + 2 * MN]) + bf2f(pu[pa + 3 * MN]) +
            b_amp[c];
  float ph = bf2f(pu[pa + 256]) + bf2f(pu[pa + 256 + MN]) + bf2f(pu[pa + 256 + 2 * MN]) +
             bf2f(pu[pa + 256 + 3 * MN]) + b_phi[c];
  a = (a > 0.f) ? (a + log1pf(expf(-a))) : log1pf(expf(a));
  ph = M_PI_F * tanhf(ph);
  float s, co;
  sincosf(ph, &s, &co);
  outr[idx] = __float2bfloat16(a * co);
  outi[idx] = __float2bfloat16(a * s);
}

// ---------------------------------------------------------------------------
// FUSED: resonator scan (blocks 0..63) || transpose-cast of the 6 remaining
// weights (blocks 64..12095) — independent work backfills the machine (r11).
// Scan: TIME-CHUNK PARALLEL (r6): contraction >= sigmoid(2.0)=0.881/step
// makes a 128-step warm-up from X=0 exact below bf16 quantization.
// ---------------------------------------------------------------------------
static constexpr int RES_P = 16;
static constexpr int RES_TC = 128;  // chunk length
static constexpr int RES_W = 128;   // warm-up length

#define RES_LOAD(buf_r, buf_i, tg)                                        \
  if ((tg) < cend) {                                                      \
    _Pragma("unroll") for (int i = 0; i < RES_P; ++i) {                   \
      buf_r[i] = __bfloat162float(ur[bbase + (size_t)((tg) + i) * NFf]);  \
      buf_i[i] = __bfloat162float(ui[bbase + (size_t)((tg) + i) * NFf]);  \
    }                                                                     \
  }

#define RES_STEP(buf_r, buf_i, tg)                                      \
  {                                                                      \
    const bool wr_ = (tg) >= cstart;                                     \
    _Pragma("unroll") for (int i = 0; i < RES_P; ++i) {                  \
      const float pr = fmaf(ar, Xr, fmaf(-ai, Xi, buf_r[i]));            \
      const float pim = fmaf(ar, Xi, fmaf(ai, Xr, buf_i[i]));            \
      const float mag = __builtin_amdgcn_sqrtf(fmaf(pr, pr, pim * pim)); \
      const float g = __builtin_amdgcn_rcpf(1.f + __expf(th - mag));     \
      Xr = pr * g;                                                       \
      Xi = pim * g;                                                      \
      if (wr_) {                                                         \
        const size_t fb = ((size_t)b * Tt + (tg) + i) * (3 * NFf);       \
        featb[fb + f] = __float2bfloat16(Xr);                            \
        featb[fb + NFf + f] = __float2bfloat16(Xi);                      \
        featb[fb + 2 * NFf + f] = __float2bfloat16(mag * g);             \
      }                                                                  \
    }                                                                    \
  }

struct STDesc {
  const float* src[6];
  __hip_bfloat16* dst[6];
  const __hip_bfloat16* ur;
  const __hip_bfloat16* ui;
  const float* omega;
  const float* ret_logit;
  const float* theta;
  __hip_bfloat16* featb;
};

__global__ __launch_bounds__(256) void scan_and_tc(STDesc d) {
  __shared__ float tile[32][33];
  const int bid = blockIdx.x;
  if (bid < 64) {
    if (threadIdx.x >= 64) return;  // scan uses 64 lanes; no barriers below
    const int tc = bid & 7;
    const int fs = (bid >> 3) & 3;
    const int b = bid >> 5;
    const int f = fs * 64 + threadIdx.x;
    const int cstart = tc * RES_TC;
    const int cend = cstart + RES_TC;
    const int tbeg = (cstart >= RES_W) ? cstart - RES_W : 0;
    const __hip_bfloat16* ur = d.ur;
    const __hip_bfloat16* ui = d.ui;
    __hip_bfloat16* featb = d.featb;
    const float dec = 1.f / (1.f + __expf(-d.ret_logit[f]));
    float so, co;
    sincosf(d.omega[f], &so, &co);
    const float ar = dec * co, ai = dec * so;
    const float th = d.theta[f];
    const size_t bbase = (size_t)b * Tt * NFf + f;
    float Xr = 0.f, Xi = 0.f;
    float Ar[RES_P], Ai[RES_P], Br[RES_P], Bi[RES_P];
    RES_LOAD(Ar, Ai, tbeg);
    for (int t0 = tbeg; t0 < cend; t0 += 2 * RES_P) {
      RES_LOAD(Br, Bi, t0 + RES_P);
      RES_STEP(Ar, Ai, t0);
      RES_LOAD(Ar, Ai, t0 + 2 * RES_P);
      RES_STEP(Br, Bi, t0 + RES_P);
    }
    return;
  }
  // transpose-cast region: W_feat, Wq, Wk, Wv, W1, W2
  constexpr int KS[6] = {768, 1024, 1024, 1024, 1024, 4096};
  constexpr int NS[6] = {1024, 1024, 1024, 1024, 4096, 1024};
  constexpr int CUM[7] = {0, 768, 1792, 2816, 3840, 7936, 12032};
  const int t = bid - 64;
  int w = 0;
#pragma unroll
  for (int i = 0; i < 6; ++i)
    if (t >= CUM[i + 1]) w = i + 1;
  tc_tile(tile, d.src[w], d.dst[w], KS[w], NS[w], t - CUM[w]);
}

// ---------------------------------------------------------------------------
// Attention phase A — MFMA (r22): S[d][e] = sum_s K[s][d]*V[s][e] per chunk.
// Stage K^T[d][s] and V^T[e][s] in LDS (same transposed-staging idiom as
// attn_out); first MFMA operand maps C-rows (d), second maps C-cols (e) —
// the twice-verified gemm_mfma convention. 8 MFMAs/wave replace ~1024
// VALU fma/thread. fp32 S out (r21 precision), fp32 Ksum by wave 0.
// ---------------------------------------------------------------------------
__global__ __launch_bounds__(256) void attn_chunk_kv(const __hip_bfloat16* __restrict__ k,
                                                     const __hip_bfloat16* __restrict__ v,
                                                     float* __restrict__ S,
                                                     float* __restrict__ Ksum) {
  __shared__ unsigned short Kt[64][72];  // K^T [d][s] bf16
  __shared__ unsigned short Vt[64][72];  // V^T [e][s] bf16
  const int g = blockIdx.x;
  const int j = g & (NCHK - 1), bh = g >> 4;
  const int b = bh >> 4, h = bh & (Hh - 1);
  const int tid = threadIdx.x;
  const size_t rowbase = (size_t)(b * Tt + j * CHK) * QS + h * DHh;
  const unsigned short* ku = (const unsigned short*)k;
  const unsigned short* vu = (const unsigned short*)v;
  for (int l = tid; l < 4096; l += 256) {
    const int s = l >> 6, d = l & 63;
    Kt[d][s] = ku[rowbase + (size_t)s * QS + d];
    Vt[d][s] = vu[rowbase + (size_t)s * QS + d];
  }
  __syncthreads();
  // Ksum: wave 0 threads sum K^T rows (LDS reads only; no barrier needed)
  if (tid < 64) {
    float ks = 0.f;
#pragma unroll
    for (int s = 0; s < 64; ++s) ks += bf2f(Kt[tid][s]);
    Ksum[(size_t)g * 64 + tid] = ks;
  }
  // MFMA: wave w owns C rows [16w,16w+16)
  const int w = tid >> 6, ln = tid & 63;
  const int fr = ln & 15;  // A-row / B-col within a 16-tile
  const int kh = ln >> 4;  // k-subgroup (s-elements kh*8.. and +32)
  const bf16x8 a0 = *(const bf16x8*)&Kt[w * 16 + fr][kh * 8];
  const bf16x8 a1 = *(const bf16x8*)&Kt[w * 16 + fr][kh * 8 + 32];
  f32x4 acc[4] = {};
#pragma unroll
  for (int ct = 0; ct < 4; ++ct) {
    const bf16x8 b0 = *(const bf16x8*)&Vt[ct * 16 + fr][kh * 8];
    const bf16x8 b1 = *(const bf16x8*)&Vt[ct * 16 + fr][kh * 8 + 32];
    acc[ct] = __builtin_amdgcn_mfma_f32_16x16x32_bf16(a0, b0, acc[ct], 0, 0, 0);
    acc[ct] = __builtin_amdgcn_mfma_f32_16x16x32_bf16(a1, b1, acc[ct], 0, 0, 0);
  }
  // C write: d = w*16 + kh*4 + r, e = ct*16 + fr
  float* Sg = S + (size_t)g * 4096;
#pragma unroll
  for (int r = 0; r < 4; ++r) {
    const int dd = w * 16 + kh * 4 + r;
#pragma unroll
    for (int ct = 0; ct < 4; ++ct) Sg[(size_t)dd * 64 + ct * 16 + fr] = acc[ct][r];
  }
}

// ---------------------------------------------------------------------------
// Attention phase B: EXCLUSIVE prefix over the 16 chunks per (b,h).
// FULLY PARALLEL (r10): one thread per chain; all fp32 (r21).
// ---------------------------------------------------------------------------
__global__ __launch_bounds__(256) void attn_prefix(float* __restrict__ S,
                                                   float* __restrict__ Ksum) {
  const int bid = blockIdx.x;
  const int tid = threadIdx.x;
  if (bid < 512) {
    const int bh = bid >> 4, r = bid & 15;
    const int de = r * 256 + tid;
    const size_t base = (size_t)bh * (NCHK * 4096) + de;
    float vv[NCHK];
#pragma unroll
    for (int j = 0; j < NCHK; ++j) vv[j] = S[base + (size_t)j * 4096];
    float run = 0.f;
#pragma unroll
    for (int j = 0; j < NCHK; ++j) {
      const float tmp = vv[j];
      S[base + (size_t)j * 4096] = run;
      run += tmp;
    }
  } else {
    const int cid = (bid - 512) * 256 + tid;  // [0, 2048)
    const int bh = cid >> 6, d = cid & 63;
    const size_t base = (size_t)bh * (NCHK * 64) + d;
    float vv[NCHK];
#pragma unroll
    for (int j = 0; j < NCHK; ++j) vv[j] = Ksum[base + (size_t)j * 64];
    float run = 0.f;
#pragma unroll
    for (int j = 0; j < NCHK; ++j) {
      const float tmp = vv[j];
      Ksum[base + (size_t)j * 64] = run;
      run += tmp;
    }
  }
}

// ---------------------------------------------------------------------------
// Attention phase C + fused per-head layernorm — FULLY MFMA.
// Stage 1 (QK^T): frags direct from global; masked scores stored as
// DOUBLE-BF16 (hi + lo) At[t][s] (r17).
// Stage 2: num[t][e] = At @ V + Q @ P via MFMA. r21: P fp32 in global,
// consumed as DOUBLE-BF16 (hi + lo). V staged transposed; 8 MFMAs per ct.
// Same operand convention as gemm_mfma. LN epilogue: row t spans 16
// consecutive lanes -> shfl_xor 1/2/4/8. All barriers are __syncthreads().
// ---------------------------------------------------------------------------
__global__ __launch_bounds__(256) void attn_out(const __hip_bfloat16* __restrict__ q,
                                                const __hip_bfloat16* __restrict__ k,
                                                const __hip_bfloat16* __restrict__ v,
                                                const float* __restrict__ S,
                                                const float* __restrict__ Ksum,
                                                const float* __restrict__ lnw,
                                                const float* __restrict__ lnb,
                                                __hip_bfloat16* __restrict__ yhb) {
  __shared__ unsigned short Atb[64][72];  // masked scores hi [t][s] bf16
  __shared__ unsigned short Atl[64][72];  // masked scores lo [t][s] bf16
  __shared__ unsigned short Vt[64][72];   // V^T [e][s] bf16
  __shared__ unsigned short Pth[64][72];  // P^T hi [e][d] bf16
  __shared__ unsigned short Ptl[64][72];  // P^T lo [e][d] bf16
  __shared__ float denp[4][64];
  __shared__ float dens[64];
  const int g = blockIdx.x;
  const int j = g & (NCHK - 1), bh = g >> 4;
  const int b = bh >> 4, h = bh & (Hh - 1);
  const int tid = threadIdx.x;
  const size_t rowbase = (size_t)(b * Tt + j * CHK) * QS + h * DHh;
  const unsigned short* qu = (const unsigned short*)q;
  const unsigned short* ku = (const unsigned short*)k;
  const unsigned short* vu = (const unsigned short*)v;
  const float* Pg = S + (size_t)g * 4096;

  // entry: stage V^T (bf16 copy) and P^T as hi/lo double-bf16 from fp32
  for (int l = tid; l < 4096; l += 256) {
    const int s = l >> 6, e = l & 63;
    Vt[e][s] = vu[rowbase + (size_t)s * QS + e];
    const float pv = Pg[l];  // l = d*64+e, d = l>>6 -> store Pt[e][d]
    const unsigned short ph = f2bf(pv);
    Pth[e][s] = ph;
    Ptl[e][s] = f2bf(pv - bf2f(ph));
  }
  // --- stage 1: QK^T via MFMA, fragments direct from global ---
  {
    const int w4 = tid >> 6, ln = tid & 63;
    const int fr = ln & 15;
    const int kh = ln >> 4;
    const unsigned short* kr = ku + rowbase + (size_t)(w4 * 16 + fr) * QS + kh * 8;
    const bf16x8 a0 = *(const bf16x8*)&kr[0];
    const bf16x8 a1 = *(const bf16x8*)&kr[32];
    f32x4 accQK[4] = {};
#pragma unroll
    for (int tt = 0; tt < 4; ++tt) {
      const unsigned short* qr = qu + rowbase + (size_t)(tt * 16 + fr) * QS + kh * 8;
      const bf16x8 b0 = *(const bf16x8*)&qr[0];
      const bf16x8 b1 = *(const bf16x8*)&qr[32];
      accQK[tt] = __builtin_amdgcn_mfma_f32_16x16x32_bf16(a0, b0, accQK[tt], 0, 0, 0);
      accQK[tt] = __builtin_amdgcn_mfma_f32_16x16x32_bf16(a1, b1, accQK[tt], 0, 0, 0);
    }
    // mask (keep s <= t), write hi/lo At[t][s], per-wave den partials
#pragma unroll
    for (int tt = 0; tt < 4; ++tt) {
      const int t = tt * 16 + fr;
      float dp = 0.f;
#pragma unroll
      for (int r = 0; r < 4; ++r) {
        const int s = w4 * 16 + kh * 4 + r;
        const float val = (s <= t) ? accQK[tt][r] : 0.f;
        const unsigned short hv = f2bf(val);
        Atb[t][s] = hv;
        Atl[t][s] = f2bf(val - bf2f(hv));
        dp += val;
      }
      dp += __shfl_xor(dp, 16);
      dp += __shfl_xor(dp, 32);
      if (ln < 16) denp[w4][t] = dp;
    }
  }
  __syncthreads();
  // --- den: qpk (q direct from global, sg-split) + denp sums ---
  {
    const int t = tid >> 2, sg = tid & 3;
    const float* pk = Ksum + (size_t)g * 64;
    const unsigned short* qr = qu + rowbase + (size_t)t * QS + sg * 16;
    float qpk = 0.f;
#pragma unroll
    for (int i = 0; i < 16; ++i) qpk = fmaf(bf2f(qr[i]), pk[sg * 16 + i], qpk);
    qpk += __shfl_xor(qpk, 1);
    qpk += __shfl_xor(qpk, 2);
    if (sg == 0)
      dens[t] = denp[0][t] + denp[1][t] + denp[2][t] + denp[3][t] + qpk + 1e-6f;
  }
  __syncthreads();
  // --- stage 2: num = At @ V + Q @ P via MFMA (hi+lo for At AND P) ---
  const int w = tid >> 6, ln = tid & 63;
  const int fr = ln & 15;
  const int kh = ln >> 4;
  const bf16x8 sa0 = *(const bf16x8*)&Atb[w * 16 + fr][kh * 8];
  const bf16x8 sa1 = *(const bf16x8*)&Atb[w * 16 + fr][kh * 8 + 32];
  const bf16x8 la0 = *(const bf16x8*)&Atl[w * 16 + fr][kh * 8];
  const bf16x8 la1 = *(const bf16x8*)&Atl[w * 16 + fr][kh * 8 + 32];
  const unsigned short* q2 = qu + rowbase + (size_t)(w * 16 + fr) * QS + kh * 8;
  const bf16x8 qa0 = *(const bf16x8*)&q2[0];
  const bf16x8 qa1 = *(const bf16x8*)&q2[32];
  f32x4 acc2[4] = {};
#pragma unroll
  for (int ct = 0; ct < 4; ++ct) {
    const bf16x8 vb0 = *(const bf16x8*)&Vt[ct * 16 + fr][kh * 8];
    const bf16x8 vb1 = *(const bf16x8*)&Vt[ct * 16 + fr][kh * 8 + 32];
    const bf16x8 ph0 = *(const bf16x8*)&Pth[ct * 16 + fr][kh * 8];
    const bf16x8 ph1 = *(const bf16x8*)&Pth[ct * 16 + fr][kh * 8 + 32];
    const bf16x8 pl0 = *(const bf16x8*)&Ptl[ct * 16 + fr][kh * 8];
    const bf16x8 pl1 = *(const bf16x8*)&Ptl[ct * 16 + fr][kh * 8 + 32];
    acc2[ct] = __builtin_amdgcn_mfma_f32_16x16x32_bf16(sa0, vb0, acc2[ct], 0, 0, 0);
    acc2[ct] = __builtin_amdgcn_mfma_f32_16x16x32_bf16(sa1, vb1, acc2[ct], 0, 0, 0);
    acc2[ct] = __builtin_amdgcn_mfma_f32_16x16x32_bf16(la0, vb0, acc2[ct], 0, 0, 0);
    acc2[ct] = __builtin_amdgcn_mfma_f32_16x16x32_bf16(la1, vb1, acc2[ct], 0, 0, 0);
    acc2[ct] = __builtin_amdgcn_mfma_f32_16x16x32_bf16(qa0, ph0, acc2[ct], 0, 0, 0);
    acc2[ct] = __builtin_amdgcn_mfma_f32_16x16x32_bf16(qa1, ph1, acc2[ct], 0, 0, 0);
    acc2[ct] = __builtin_amdgcn_mfma_f32_16x16x32_bf16(qa0, pl0, acc2[ct], 0, 0, 0);
    acc2[ct] = __builtin_amdgcn_mfma_f32_16x16x32_bf16(qa1, pl1, acc2[ct], 0, 0, 0);
  }
  // --- epilogue: divide by den, per-head LN (row t in 16 consecutive lanes) ---
  unsigned short* yb = (unsigned short*)yhb;
#pragma unroll
  for (int r = 0; r < 4; ++r) {
    const int t = w * 16 + kh * 4 + r;
    const float inv = 1.f / dens[t];
    float o[4];
    float s1 = 0.f, s2 = 0.f;
#pragma unroll
    for (int ct = 0; ct < 4; ++ct) {
      o[ct] = acc2[ct][r] * inv;
      s1 += o[ct];
      s2 += o[ct] * o[ct];
    }
#pragma unroll
    for (int m = 1; m < 16; m <<= 1) {
      s1 += __shfl_xor(s1, m);
      s2 += __shfl_xor(s2, m);
    }
    const float mean = s1 * (1.f / 64.f);
    const float var = s2 * (1.f / 64.f) - mean * mean;
    const float rsv = rsqrtf(var + 1e-5f);
    unsigned short* yg = yb + (size_t)(b * Tt + j * CHK + t) * Dd + h * DHh;
#pragma unroll
    for (int ct = 0; ct < 4; ++ct) {
      const int e = ct * 16 + fr;
      const float rr = (o[ct] - mean) * rsv * lnw[h * DHh + e] + lnb[h * DHh + e];
      yg[e] = f2bf(rr);
    }
  }
}

// ---------------------------------------------------------------------------
// Fused FFN2-reduce (4 bf16 split-K partials) + bias + relu + residual +
// final layernorm over D=1024.
// ---------------------------------------------------------------------------
__global__ __launch_bounds__(256) void final_ln(const float* __restrict__ x,
                                                const __hip_bfloat16* __restrict__ part,
                                                const float* __restrict__ b2,
                                                const float* __restrict__ w,
                                                const float* __restrict__ bb,
                                                float* __restrict__ out) {
  __shared__ float r1[4], r2[4];
  const int row = blockIdx.x;
  const int tid = threadIdx.x;
  const size_t off = (size_t)row * Dd + tid * 4;
  const size_t MN = (size_t)Mm * Dd;
  float acc4[4] = {0.f, 0.f, 0.f, 0.f};
#pragma unroll
  for (int z = 0; z < 4; ++z) {
    const ushort4 u = *(const ushort4*)&part[off + (size_t)z * MN];
    acc4[0] += bf2f(u.x);
    acc4[1] += bf2f(u.y);
    acc4[2] += bf2f(u.z);
    acc4[3] += bf2f(u.w);
  }
  const float4 bv = *(const float4*)&b2[tid * 4];
  const float4 xa = *(const float4*)&x[off];
  float z[4];
  z[0] = xa.x + fmaxf(acc4[0] + bv.x, 0.f);
  z[1] = xa.y + fmaxf(acc4[1] + bv.y, 0.f);
  z[2] = xa.z + fmaxf(acc4[2] + bv.z, 0.f);
  z[3] = xa.w + fmaxf(acc4[3] + bv.w, 0.f);
  float s1 = z[0] + z[1] + z[2] + z[3];
  float s2 = z[0] * z[0] + z[1] * z[1] + z[2] * z[2] + z[3] * z[3];
#pragma unroll
  for (int o = 1; o < 64; o <<= 1) {
    s1 += __shfl_xor(s1, o);
    s2 += __shfl_xor(s2, o);
  }
  const int wid = tid >> 6;
  if ((tid & 63) == 0) {
    r1[wid] = s1;
    r2[wid] = s2;
  }
  __syncthreads();
  const float t1 = r1[0] + r1[1] + r1[2] + r1[3];
  const float t2 = r2[0] + r2[1] + r2[2] + r2[3];
  const float mu = t1 * (1.f / Dd);
  const float var = t2 * (1.f / Dd) - mu * mu;
  const float rsv = rsqrtf(var + 1e-5f);
  float4 o4;
  float* op = &o4.x;
#pragma unroll
  for (int jj = 0; jj < 4; ++jj) op[jj] = (z[jj] - mu) * rsv * w[tid * 4 + jj] + bb[tid * 4 + jj];
  *(float4*)&out[off] = o4;
}

// ---------------------------------------------------------------------------
extern "C" void kernel_launch(void* const* d_in, const int* in_sizes, int n_in,
                              void* d_out, int out_size, void* d_ws, size_t ws_size,
                              hipStream_t stream) {
  const float* x = (const float*)d_in[0];
  const float* W_amp = (const float*)d_in[1];
  const float* b_amp = (const float*)d_in[2];
  const float* W_phi = (const float*)d_in[3];
  const float* b_phi = (const float*)d_in[4];
  const float* omega = (const float*)d_in[5];
  const float* ret_logit = (const float*)d_in[6];
  const float* theta = (const float*)d_in[7];
  const float* W_feat = (const float*)d_in[8];
  const float* b_feat = (const float*)d_in[9];
  const float* Wq = (const float*)d_in[10];
  const float* Wk = (const float*)d_in[11];
  const float* Wv = (const float*)d_in[12];
  const float* lnh_w = (const float*)d_in[13];
  const float* lnh_b = (const float*)d_in[14];
  const float* W1 = (const float*)d_in[15];
  const float* b1 = (const float*)d_in[16];
  const float* W2 = (const float*)d_in[17];
  const float* b2 = (const float*)d_in[18];
  const float* ln_w = (const float*)d_in[19];
  const float* ln_b = (const float*)d_in[20];

  // ---- workspace bump allocator (256B aligned); dedicated buffers ----
  char* p = (char*)d_ws;
  auto alloc = [&](size_t bytes) {
    char* r = p;
    p += (bytes + 255) & ~(size_t)255;
    return r;
  };
  __hip_bfloat16* xb = (__hip_bfloat16*)alloc((size_t)Mm * Dd * 2);   // later: featb
  __hip_bfloat16* urh = (__hip_bfloat16*)alloc((size_t)Mm * NFf * 2);
  __hip_bfloat16* uih = (__hip_bfloat16*)alloc((size_t)Mm * NFf * 2);
  __hip_bfloat16* WTamp = (__hip_bfloat16*)alloc((size_t)NFf * Dd * 2);  // +WTphi contiguous
  __hip_bfloat16* WTphi = (__hip_bfloat16*)alloc((size_t)NFf * Dd * 2);
  __hip_bfloat16* WTfeat = (__hip_bfloat16*)alloc((size_t)Dd * 3 * NFf * 2);
  __hip_bfloat16* WTq = (__hip_bfloat16*)alloc((size_t)Dd * Dd * 2);  // +k+v contiguous
  __hip_bfloat16* WTk = (__hip_bfloat16*)alloc((size_t)Dd * Dd * 2);
  __hip_bfloat16* WTv = (__hip_bfloat16*)alloc((size_t)Dd * Dd * 2);
  __hip_bfloat16* WT1 = (__hip_bfloat16*)alloc((size_t)Rr * Dd * 2);
  __hip_bfloat16* WT2 = (__hip_bfloat16*)alloc((size_t)Dd * Rr * 2);
  __hip_bfloat16* hb = (__hip_bfloat16*)alloc((size_t)Mm * Dd * 2);
  __hip_bfloat16* qkvb = (__hip_bfloat16*)alloc((size_t)Mm * QS * 2);  // 12 MB
  __hip_bfloat16* yhb = (__hip_bfloat16*)alloc((size_t)Mm * Dd * 2);   // 4 MB
  float* S = (float*)alloc((size_t)Bb * Hh * NCHK * 4096 * 4);         // 8 MB fp32 (r21)
  float* Ksum = (float*)alloc((size_t)Bb * Hh * NCHK * 64 * 4);
  __hip_bfloat16* f1b = (__hip_bfloat16*)alloc((size_t)Mm * Rr * 2);   // 16 MB
  __hip_bfloat16* pamp = (__hip_bfloat16*)alloc((size_t)4 * Mm * 512 * 2);   // 8 MB dedicated
  __hip_bfloat16* pffn2 = (__hip_bfloat16*)alloc((size_t)4 * Mm * Dd * 2);   // 16 MB dedicated

  __hip_bfloat16* featb = xb;  // xb dead after ampphi GEMM (stream-ordered)
  const __hip_bfloat16* q = qkvb;
  const __hip_bfloat16* k = qkvb + 1024;
  const __hip_bfloat16* v = qkvb + 2048;
  float* out = (float*)d_out;

  const dim3 blk(256);

  // 0: amp/phi weight transposes + x cast (what the first GEMM needs)
  tc_first<<<dim3(2560), blk, 0, stream>>>(W_amp, W_phi, WTamp, WTphi, x, xb);

  // 1: fused amp/phi projection, split-K=4 (256 blocks, bf16 partials), then
  //    fused reduce + softplus/tanh + polar -> bf16 u
  gemm_mfma<EPI_NONE, 1, 4><<<dim3(512 / 128, Mm / 128, 4), blk, 0, stream>>>(
      (const short*)xb, (const short*)WTamp, nullptr, nullptr, pamp, Mm, 512, Dd);
  reduce_polar<<<dim3(Mm * NFf / 256), blk, 0, stream>>>(pamp, b_amp, b_phi, urh, uih);

  // 2: FUSED resonator scan (64 blocks) || remaining weight transposes
  STDesc st;
  st.src[0] = W_feat; st.dst[0] = WTfeat;
  st.src[1] = Wq; st.dst[1] = WTq;
  st.src[2] = Wk; st.dst[2] = WTk;
  st.src[3] = Wv; st.dst[3] = WTv;
  st.src[4] = W1; st.dst[4] = WT1;
  st.src[5] = W2; st.dst[5] = WT2;
  st.ur = urh; st.ui = uih;
  st.omega = omega; st.ret_logit = ret_logit; st.theta = theta;
  st.featb = featb;
  scan_and_tc<<<dim3(64 + 12032), blk, 0, stream>>>(st);

  // 3: feat projection -> h (bf16)
  gemm_mfma<EPI_RELU, 1, 0><<<dim3(Dd / 128, Mm / 128), blk, 0, stream>>>(
      (const short*)featb, (const short*)WTfeat, b_feat, nullptr, hb, Mm, Dd, 3 * NFf);

  // 4: fused q,k,v projection -> bf16 qkvb (384 blocks)
  gemm_mfma<EPI_QKV, 1, 0><<<dim3(QS / 128, Mm / 128), blk, 0, stream>>>(
      (const short*)hb, (const short*)WTq, nullptr, nullptr, qkvb, Mm, QS, Dd);

  // 5: chunked causal linear attention (+ fused per-head LN in attn_out)
  attn_chunk_kv<<<dim3(Bb * Hh * NCHK), blk, 0, stream>>>(k, v, S, Ksum);
  attn_prefix<<<dim3(520), blk, 0, stream>>>(S, Ksum);
  attn_out<<<dim3(Bb * Hh * NCHK), blk, 0, stream>>>(q, k, v, S, Ksum, lnh_w, lnh_b, yhb);

  // 6: FFN1 -> f1b (bf16); 512 blocks = 2 blocks/CU (dbuf LDS cap)
  gemm_mfma<EPI_RELU, 1, 0><<<dim3(Rr / 128, Mm / 128), blk, 0, stream>>>(
      (const short*)yhb, (const short*)WT1, b1, nullptr, f1b, Mm, Rr, Dd);

  // 7: FFN2 split-K=4, bf16 partials -> pffn2; 512 blocks = 2 blocks/CU
  gemm_mfma<EPI_NONE, 1, 4><<<dim3(Dd / 128, Mm / 128, 4), blk, 0, stream>>>(
      (const short*)f1b, (const short*)WT2, nullptr, nullptr, pffn2, Mm, Dd, Rr);

  // 8: fused reduce(4x bf16) + bias + relu + residual + final layernorm
  final_ln<<<dim3(Mm), blk, 0, stream>>>(x, pffn2, b2, ln_w, ln_b, out);
}

// Round 25
// 158.661 us; speedup vs baseline: 1.0355x; 1.0006x over previous
//
#include <hip/hip_runtime.h>
#include <hip/hip_bf16.h>
#include <math.h>

#ifndef M_PI_F
#define M_PI_F 3.14159265358979323846f
#endif

static constexpr int Bb = 2, Tt = 1024, Dd = 1024, Hh = 16, DHh = 64, NFf = 256, Rr = 4096;
static constexpr int Mm = Bb * Tt;
static constexpr int CHK = 64, NCHK = Tt / CHK;  // attention chunking
static constexpr int QS = 3072;                  // fused qkv row stride

enum Epi { EPI_NONE = 0, EPI_RELU, EPI_QKV };

typedef __attribute__((ext_vector_type(8))) short bf16x8;
typedef __attribute__((ext_vector_type(4))) float f32x4;

__device__ inline float bf2f(unsigned short u) {
  union { unsigned int i; float f; } c;
  c.i = (unsigned int)u << 16;
  return c.f;
}

__device__ inline unsigned short f2bf(float f) {
  __hip_bfloat16 h = __float2bfloat16(f);
  return *(unsigned short*)&h;
}

// ---------------------------------------------------------------------------
// async global->LDS, 16B per lane. LDS dest is wave-uniform base; HW adds
// lane*16. Global address is per-lane.
// ---------------------------------------------------------------------------
__device__ inline void gload16(const short* g, short* l) {
  __builtin_amdgcn_global_load_lds(
      (const __attribute__((address_space(1))) unsigned int*)g,
      (__attribute__((address_space(3))) unsigned int*)l, 16, 0, 0);
}

// ---------------------------------------------------------------------------
// bf16 MFMA GEMM: C[M,N] = epi(A[M,K] @ BT[N,K]^T + bias)
// 128x128 tile, BK=64, 4 waves (2x2), each 64x64 via 4x4 frags of 16x16x32.
// - Double-buffered K-loop with counted vmcnt (r7). r18 A/B: single-buffer
//   at 4 blocks/CU REGRESSED — counted prefetch off the critical path beats
//   extra co-residency beyond 2 blocks/CU.
// - r20 RACE FIX (kept): sched_barrier(0) + s_waitcnt lgkmcnt(0) before the
//   done-reading s_barrier (s_barrier does NOT drain LDS ops; rule #18).
// - LDS XOR bank-swizzle (rule #21 both-sides involution).
// - Bijective XCD swizzle (m204) for A-panel L2 reuse per XCD.
// - SPLITK: partial (fp32 Cf / bf16 Cb) at +z*M*N into DEDICATED buffers.
//   r25 numerics lesson (r24 failed at 0.125): bf16 partials are affordable
//   ONLY where downstream is LN-normalized (FFN2); pipeline-head splits
//   (feat) must use fp32 partials; ampphi stays at the proven split-4.
// ---------------------------------------------------------------------------
#define GSTAGE(bufsel, kk0)                                           \
  _Pragma("unroll") for (int si = 0; si < 4; ++si) {                  \
    const int s = wid + si * 4;                                       \
    gload16(A + (size_t)(m0 + s * 8 + srow) * ldk + (kk0) + skk,      \
            &lA[(bufsel) * 8192 + s * 512]);                          \
    gload16(BT + (size_t)(n0 + s * 8 + srow) * ldk + (kk0) + skk,     \
            &lB[(bufsel) * 8192 + s * 512]);                          \
  }

template <int EPI, int OUTBF, int SPLITK>
__global__ __launch_bounds__(256) void gemm_mfma(const short* __restrict__ A,
                                                 const short* __restrict__ BT,
                                                 const float* __restrict__ bias,
                                                 float* __restrict__ Cf,
                                                 __hip_bfloat16* __restrict__ Cb,
                                                 int M, int N, int ldk) {
  __shared__ short lA[2 * 128 * 64];
  __shared__ short lB[2 * 128 * 64];
  const int tid = threadIdx.x;
  const int wid = tid >> 6, lane = tid & 63;

  // XCD-aware bijective block swizzle (grids here always have nwg % 8 == 0)
  const int nwg = gridDim.x * gridDim.y;
  const int wg = blockIdx.y * gridDim.x + blockIdx.x;
  const int qq = nwg >> 3, rr = nwg & 7;
  const int xcd = wg & 7, idx = wg >> 3;
  const int wg2 = (xcd < rr ? xcd * (qq + 1) : rr * (qq + 1) + (xcd - rr) * qq) + idx;
  const int bx = wg2 % gridDim.x, by = wg2 / gridDim.x;

  const int m0 = by * 128, n0 = bx * 128;
  const int wm = (wid >> 1) * 64, wn = (wid & 1) * 64;
  const int srow = lane >> 3;                         // row within 8-row slab
  const int skk = (((lane & 7) ^ (lane >> 3)) << 3);  // swizzled k offset (elems)

  int kstart = 0, klen = ldk;
  if (SPLITK > 1) {
    klen = ldk / SPLITK;
    kstart = blockIdx.z * klen;
    if (OUTBF)
      Cb += (size_t)blockIdx.z * M * N;
    else
      Cf += (size_t)blockIdx.z * M * N;
  }
  const int kend = kstart + klen;

  f32x4 acc[4][4] = {};

  GSTAGE(0, kstart);  // prologue: 8 loads/wave in flight
  int cur = 0;
  for (int k0 = kstart; k0 < kend; k0 += 64) {
    if (k0 + 64 < kend) {
      GSTAGE(cur ^ 1, k0 + 64);                         // 16 in flight
      asm volatile("s_waitcnt vmcnt(8)" ::: "memory");  // oldest 8 (cur buf) done
    } else {
      asm volatile("s_waitcnt vmcnt(0)" ::: "memory");
    }
    asm volatile("s_barrier" ::: "memory");
    const short* bA = &lA[cur * 8192];
    const short* bB = &lB[cur * 8192];
#pragma unroll
    for (int kk = 0; kk < 2; ++kk) {
      const int krd = kk * 32 + (lane >> 4) * 8;
      const int rsel = lane & 15;
      const int kswz = krd ^ ((rsel & 7) << 3);  // same involution as store side
      bf16x8 af[4], bfr[4];
#pragma unroll
      for (int i = 0; i < 4; ++i) {
        af[i] = *(const bf16x8*)&bA[(wm + i * 16 + rsel) * 64 + kswz];
        bfr[i] = *(const bf16x8*)&bB[(wn + i * 16 + rsel) * 64 + kswz];
      }
#pragma unroll
      for (int i = 0; i < 4; ++i)
#pragma unroll
        for (int j = 0; j < 4; ++j)
          acc[i][j] = __builtin_amdgcn_mfma_f32_16x16x32_bf16(af[i], bfr[j], acc[i][j], 0, 0, 0);
    }
    // race fix: pin MFMA cluster, retire ALL LDS reads before signaling the
    // buffer reusable. vmcnt prefetch stays in flight (the dbuf win).
    __builtin_amdgcn_sched_barrier(0);
    asm volatile("s_waitcnt lgkmcnt(0)" ::: "memory");
    asm volatile("s_barrier" ::: "memory");
    cur ^= 1;
  }

  const int crow = (lane >> 4) * 4;
  const int ccol = lane & 15;
#pragma unroll
  for (int j = 0; j < 4; ++j) {
    const int col = n0 + wn + j * 16 + ccol;
    const float bv = bias ? bias[col] : 0.f;
#pragma unroll
    for (int i = 0; i < 4; ++i) {
#pragma unroll
      for (int r = 0; r < 4; ++r) {
        float v = acc[i][j][r] + bv;
        const int row = m0 + wm + i * 16 + crow + r;
        if (EPI == EPI_QKV) {
          const float vv = (col < 2048) ? fmaxf(v, 0.f) : v;
          Cb[(size_t)row * QS + col] = __float2bfloat16(vv);
        } else {
          if (EPI == EPI_RELU) v = fmaxf(v, 0.f);
          const size_t off = (size_t)row * N + col;
          if (OUTBF)
            Cb[off] = __float2bfloat16(v);
          else
            Cf[off] = v;
        }
      }
    }
  }
}

// ---------------------------------------------------------------------------
// 32x32 transpose-cast tile helper: W[K,N] f32 -> WT[N,K] bf16.
// ---------------------------------------------------------------------------
__device__ __forceinline__ void tc_tile(float (*tile)[33], const float* __restrict__ W,
                                        __hip_bfloat16* __restrict__ WT, int K, int N,
                                        int tlocal) {
  const int tilesN = N / 32;
  const int bk = (tlocal / tilesN) * 32, bn = (tlocal % tilesN) * 32;
  const int tx = threadIdx.x & 31, ty = threadIdx.x >> 5;  // 32x8
#pragma unroll
  for (int r = 0; r < 32; r += 8) tile[ty + r][tx] = W[(size_t)(bk + ty + r) * N + bn + tx];
  __syncthreads();
#pragma unroll
  for (int r = 0; r < 32; r += 8)
    WT[(size_t)(bn + ty + r) * K + bk + tx] = __float2bfloat16(tile[tx][ty + r]);
}

// ---------------------------------------------------------------------------
// Head kernel: W_amp / W_phi transpose-cast + x f32->bf16 cast.
// ---------------------------------------------------------------------------
__global__ __launch_bounds__(256) void tc_first(const float* __restrict__ W_amp,
                                                const float* __restrict__ W_phi,
                                                __hip_bfloat16* __restrict__ WTamp,
                                                __hip_bfloat16* __restrict__ WTphi,
                                                const float* __restrict__ x,
                                                __hip_bfloat16* __restrict__ xb) {
  __shared__ float tile[32][33];
  const int bid = blockIdx.x;
  if (bid >= 512) {
    const int i = ((bid - 512) * 256 + threadIdx.x) * 4;
    const float4 v = *(const float4*)&x[i];
    xb[i + 0] = __float2bfloat16(v.x);
    xb[i + 1] = __float2bfloat16(v.y);
    xb[i + 2] = __float2bfloat16(v.z);
    xb[i + 3] = __float2bfloat16(v.w);
    return;
  }
  if (bid < 256)
    tc_tile(tile, W_amp, WTamp, 1024, 256, bid);
  else
    tc_tile(tile, W_phi, WTphi, 1024, 256, bid - 256);
}

// ---------------------------------------------------------------------------
// amp/phi split-K reduce (4 bf16 partials — r23-proven) fused with
// activations and polar->cartesian. part: [4][M][512] bf16.
// ---------------------------------------------------------------------------
__global__ __launch_bounds__(256) void reduce_polar(const __hip_bfloat16* __restrict__ part,
                                                    const float* __restrict__ b_amp,
                                                    const float* __restrict__ b_phi,
                                                    __hip_bfloat16* __restrict__ outr,
                                                    __hip_bfloat16* __restrict__ outi) {
  const int idx = blockIdx.x * 256 + threadIdx.x;  // [0, M*NF)
  const int row = idx >> 8, c = idx & 255;
  const size_t MN = (size_t)Mm * 512;
  const size_t pa = (size_t)row * 512 + c;
  const unsigned short* pu = (const unsigned short*)part;
  float a = bf2f(pu[pa]) + bf2f(pu[pa + MN]) + bf2f(pu[pa + 2 * MN]) + bf2f(pu[pa + 3 * MN]) +
            b_amp[c];
  float ph = bf2f(pu[pa + 256]) + bf2f(pu[pa + 256 + MN]) + bf2f(pu[pa + 256 + 2 * MN]) +
             bf2f(pu[pa + 256 + 3 * MN]) + b_phi[c];
  a = (a > 0.f) ? (a + log1pf(expf(-a))) : log1pf(expf(a));
  ph = M_PI_F * tanhf(ph);
  float s, co;
  sincosf(ph, &s, &co);
  outr[idx] = __float2bfloat16(a * co);
  outi[idx] = __float2bfloat16(a * s);
}

// ---------------------------------------------------------------------------
// feat split-K reduce (r25): hb = bf16(relu(p0 + p1 + b_feat)).
// part layout: [2][M][1024] FP32 (r24's bf16 partials blew the error budget
// at the pipeline head — fp32 partials are sum-order-only).
// ---------------------------------------------------------------------------
__global__ __launch_bounds__(256) void reduce_feat(const float* __restrict__ part,
                                                   const float* __restrict__ b_feat,
                                                   __hip_bfloat16* __restrict__ hb) {
  const size_t base = ((size_t)blockIdx.x * 256 + threadIdx.x) * 4;
  const size_t MN = (size_t)Mm * Dd;
  const float4 p0 = *(const float4*)&part[base];
  const float4 p1 = *(const float4*)&part[base + MN];
  const int col = (int)(base & (Dd - 1));
  const float4 bv = *(const float4*)&b_feat[col];
  ushort4 o;
  o.x = f2bf(fmaxf(p0.x + p1.x + bv.x, 0.f));
  o.y = f2bf(fmaxf(p0.y + p1.y + bv.y, 0.f));
  o.z = f2bf(fmaxf(p0.z + p1.z + bv.z, 0.f));
  o.w = f2bf(fmaxf(p0.w + p1.w + bv.w, 0.f));
  *(ushort4*)&((unsigned short*)hb)[base] = o;
}

// ---------------------------------------------------------------------------
// FUSED: resonator scan (blocks 0..63) || transpose-cast of the 6 remaining
// weights (blocks 64..12095) — independent work backfills the machine (r11).
// Scan: TIME-CHUNK PARALLEL (r6): contraction >= sigmoid(2.0)=0.881/step
// makes a 128-step warm-up from X=0 exact below bf16 quantization.
// ---------------------------------------------------------------------------
static constexpr int RES_P = 16;
static constexpr int RES_TC = 128;  // chunk length
static constexpr int RES_W = 128;   // warm-up length

#define RES_LOAD(buf_r, buf_i, tg)                                        \
  if ((tg) < cend) {                                                      \
    _Pragma("unroll") for (int i = 0; i < RES_P; ++i) {                   \
      buf_r[i] = __bfloat162float(ur[bbase + (size_t)((tg) + i) * NFf]);  \
      buf_i[i] = __bfloat162float(ui[bbase + (size_t)((tg) + i) * NFf]);  \
    }                                                                     \
  }

#define RES_STEP(buf_r, buf_i, tg)                                      \
  {                                                                      \
    const bool wr_ = (tg) >= cstart;                                     \
    _Pragma("unroll") for (int i = 0; i < RES_P; ++i) {                  \
      const float pr = fmaf(ar, Xr, fmaf(-ai, Xi, buf_r[i]));            \
      const float pim = fmaf(ar, Xi, fmaf(ai, Xr, buf_i[i]));            \
      const float mag = __builtin_amdgcn_sqrtf(fmaf(pr, pr, pim * pim)); \
      const float g = __builtin_amdgcn_rcpf(1.f + __expf(th - mag));     \
      Xr = pr * g;                                                       \
      Xi = pim * g;                                                      \
      if (wr_) {                                                         \
        const size_t fb = ((size_t)b * Tt + (tg) + i) * (3 * NFf);       \
        featb[fb + f] = __float2bfloat16(Xr);                            \
        featb[fb + NFf + f] = __float2bfloat16(Xi);                      \
        featb[fb + 2 * NFf + f] = __float2bfloat16(mag * g);             \
      }                                                                  \
    }                                                                    \
  }

struct STDesc {
  const float* src[6];
  __hip_bfloat16* dst[6];
  const __hip_bfloat16* ur;
  const __hip_bfloat16* ui;
  const float* omega;
  const float* ret_logit;
  const float* theta;
  __hip_bfloat16* featb;
};

__global__ __launch_bounds__(256) void scan_and_tc(STDesc d) {
  __shared__ float tile[32][33];
  const int bid = blockIdx.x;
  if (bid < 64) {
    if (threadIdx.x >= 64) return;  // scan uses 64 lanes; no barriers below
    const int tc = bid & 7;
    const int fs = (bid >> 3) & 3;
    const int b = bid >> 5;
    const int f = fs * 64 + threadIdx.x;
    const int cstart = tc * RES_TC;
    const int cend = cstart + RES_TC;
    const int tbeg = (cstart >= RES_W) ? cstart - RES_W : 0;
    const __hip_bfloat16* ur = d.ur;
    const __hip_bfloat16* ui = d.ui;
    __hip_bfloat16* featb = d.featb;
    const float dec = 1.f / (1.f + __expf(-d.ret_logit[f]));
    float so, co;
    sincosf(d.omega[f], &so, &co);
    const float ar = dec * co, ai = dec * so;
    const float th = d.theta[f];
    const size_t bbase = (size_t)b * Tt * NFf + f;
    float Xr = 0.f, Xi = 0.f;
    float Ar[RES_P], Ai[RES_P], Br[RES_P], Bi[RES_P];
    RES_LOAD(Ar, Ai, tbeg);
    for (int t0 = tbeg; t0 < cend; t0 += 2 * RES_P) {
      RES_LOAD(Br, Bi, t0 + RES_P);
      RES_STEP(Ar, Ai, t0);
      RES_LOAD(Ar, Ai, t0 + 2 * RES_P);
      RES_STEP(Br, Bi, t0 + RES_P);
    }
    return;
  }
  // transpose-cast region: W_feat, Wq, Wk, Wv, W1, W2
  constexpr int KS[6] = {768, 1024, 1024, 1024, 1024, 4096};
  constexpr int NS[6] = {1024, 1024, 1024, 1024, 4096, 1024};
  constexpr int CUM[7] = {0, 768, 1792, 2816, 3840, 7936, 12032};
  const int t = bid - 64;
  int w = 0;
#pragma unroll
  for (int i = 0; i < 6; ++i)
    if (t >= CUM[i + 1]) w = i + 1;
  tc_tile(tile, d.src[w], d.dst[w], KS[w], NS[w], t - CUM[w]);
}

// ---------------------------------------------------------------------------
// Attention phase A — MFMA (r22): S[d][e] = sum_s K[s][d]*V[s][e] per chunk.
// Stage K^T[d][s] and V^T[e][s] in LDS; first MFMA operand maps C-rows (d),
// second maps C-cols (e). fp32 S out (r21), fp32 Ksum by wave 0.
// ---------------------------------------------------------------------------
__global__ __launch_bounds__(256) void attn_chunk_kv(const __hip_bfloat16* __restrict__ k,
                                                     const __hip_bfloat16* __restrict__ v,
                                                     float* __restrict__ S,
                                                     float* __restrict__ Ksum) {
  __shared__ unsigned short Kt[64][72];  // K^T [d][s] bf16
  __shared__ unsigned short Vt[64][72];  // V^T [e][s] bf16
  const int g = blockIdx.x;
  const int j = g & (NCHK - 1), bh = g >> 4;
  const int b = bh >> 4, h = bh & (Hh - 1);
  const int tid = threadIdx.x;
  const size_t rowbase = (size_t)(b * Tt + j * CHK) * QS + h * DHh;
  const unsigned short* ku = (const unsigned short*)k;
  const unsigned short* vu = (const unsigned short*)v;
  for (int l = tid; l < 4096; l += 256) {
    const int s = l >> 6, d = l & 63;
    Kt[d][s] = ku[rowbase + (size_t)s * QS + d];
    Vt[d][s] = vu[rowbase + (size_t)s * QS + d];
  }
  __syncthreads();
  // Ksum: wave 0 threads sum K^T rows (LDS reads only; no barrier needed)
  if (tid < 64) {
    float ks = 0.f;
#pragma unroll
    for (int s = 0; s < 64; ++s) ks += bf2f(Kt[tid][s]);
    Ksum[(size_t)g * 64 + tid] = ks;
  }
  // MFMA: wave w owns C rows [16w,16w+16)
  const int w = tid >> 6, ln = tid & 63;
  const int fr = ln & 15;  // A-row / B-col within a 16-tile
  const int kh = ln >> 4;  // k-subgroup (s-elements kh*8.. and +32)
  const bf16x8 a0 = *(const bf16x8*)&Kt[w * 16 + fr][kh * 8];
  const bf16x8 a1 = *(const bf16x8*)&Kt[w * 16 + fr][kh * 8 + 32];
  f32x4 acc[4] = {};
#pragma unroll
  for (int ct = 0; ct < 4; ++ct) {
    const bf16x8 b0 = *(const bf16x8*)&Vt[ct * 16 + fr][kh * 8];
    const bf16x8 b1 = *(const bf16x8*)&Vt[ct * 16 + fr][kh * 8 + 32];
    acc[ct] = __builtin_amdgcn_mfma_f32_16x16x32_bf16(a0, b0, acc[ct], 0, 0, 0);
    acc[ct] = __builtin_amdgcn_mfma_f32_16x16x32_bf16(a1, b1, acc[ct], 0, 0, 0);
  }
  // C write: d = w*16 + kh*4 + r, e = ct*16 + fr
  float* Sg = S + (size_t)g * 4096;
#pragma unroll
  for (int r = 0; r < 4; ++r) {
    const int dd = w * 16 + kh * 4 + r;
#pragma unroll
    for (int ct = 0; ct < 4; ++ct) Sg[(size_t)dd * 64 + ct * 16 + fr] = acc[ct][r];
  }
}

// ---------------------------------------------------------------------------
// Attention phase B: EXCLUSIVE prefix over the 16 chunks per (b,h).
// FULLY PARALLEL (r10): one thread per chain; all fp32 (r21).
// ---------------------------------------------------------------------------
__global__ __launch_bounds__(256) void attn_prefix(float* __restrict__ S,
                                                   float* __restrict__ Ksum) {
  const int bid = blockIdx.x;
  const int tid = threadIdx.x;
  if (bid < 512) {
    const int bh = bid >> 4, r = bid & 15;
    const int de = r * 256 + tid;
    const size_t base = (size_t)bh * (NCHK * 4096) + de;
    float vv[NCHK];
#pragma unroll
    for (int j = 0; j < NCHK; ++j) vv[j] = S[base + (size_t)j * 4096];
    float run = 0.f;
#pragma unroll
    for (int j = 0; j < NCHK; ++j) {
      const float tmp = vv[j];
      S[base + (size_t)j * 4096] = run;
      run += tmp;
    }
  } else {
    const int cid = (bid - 512) * 256 + tid;  // [0, 2048)
    const int bh = cid >> 6, d = cid & 63;
    const size_t base = (size_t)bh * (NCHK * 64) + d;
    float vv[NCHK];
#pragma unroll
    for (int j = 0; j < NCHK; ++j) vv[j] = Ksum[base + (size_t)j * 64];
    float run = 0.f;
#pragma unroll
    for (int j = 0; j < NCHK; ++j) {
      const float tmp = vv[j];
      Ksum[base + (size_t)j * 64] = run;
      run += tmp;
    }
  }
}

// ---------------------------------------------------------------------------
// Attention phase C + fused per-head layernorm — FULLY MFMA.
// Stage 1 (QK^T): frags direct from global; masked scores stored as
// DOUBLE-BF16 (hi + lo) At[t][s] (r17).
// Stage 2: num[t][e] = At @ V + Q @ P via MFMA. r21: P fp32 in global,
// consumed as DOUBLE-BF16 (hi + lo). V staged transposed; 8 MFMAs per ct.
// Same operand convention as gemm_mfma. LN epilogue: row t spans 16
// consecutive lanes -> shfl_xor 1/2/4/8. All barriers are __syncthreads().
// ---------------------------------------------------------------------------
__global__ __launch_bounds__(256) void attn_out(const __hip_bfloat16* __restrict__ q,
                                                const __hip_bfloat16* __restrict__ k,
                                                const __hip_bfloat16* __restrict__ v,
                                                const float* __restrict__ S,
                                                const float* __restrict__ Ksum,
                                                const float* __restrict__ lnw,
                                                const float* __restrict__ lnb,
                                                __hip_bfloat16* __restrict__ yhb) {
  __shared__ unsigned short Atb[64][72];  // masked scores hi [t][s] bf16
  __shared__ unsigned short Atl[64][72];  // masked scores lo [t][s] bf16
  __shared__ unsigned short Vt[64][72];   // V^T [e][s] bf16
  __shared__ unsigned short Pth[64][72];  // P^T hi [e][d] bf16
  __shared__ unsigned short Ptl[64][72];  // P^T lo [e][d] bf16
  __shared__ float denp[4][64];
  __shared__ float dens[64];
  const int g = blockIdx.x;
  const int j = g & (NCHK - 1), bh = g >> 4;
  const int b = bh >> 4, h = bh & (Hh - 1);
  const int tid = threadIdx.x;
  const size_t rowbase = (size_t)(b * Tt + j * CHK) * QS + h * DHh;
  const unsigned short* qu = (const unsigned short*)q;
  const unsigned short* ku = (const unsigned short*)k;
  const unsigned short* vu = (const unsigned short*)v;
  const float* Pg = S + (size_t)g * 4096;

  // entry: stage V^T (bf16 copy) and P^T as hi/lo double-bf16 from fp32
  for (int l = tid; l < 4096; l += 256) {
    const int s = l >> 6, e = l & 63;
    Vt[e][s] = vu[rowbase + (size_t)s * QS + e];
    const float pv = Pg[l];  // l = d*64+e, d = l>>6 -> store Pt[e][d]
    const unsigned short ph = f2bf(pv);
    Pth[e][s] = ph;
    Ptl[e][s] = f2bf(pv - bf2f(ph));
  }
  // --- stage 1: QK^T via MFMA, fragments direct from global ---
  {
    const int w4 = tid >> 6, ln = tid & 63;
    const int fr = ln & 15;
    const int kh = ln >> 4;
    const unsigned short* kr = ku + rowbase + (size_t)(w4 * 16 + fr) * QS + kh * 8;
    const bf16x8 a0 = *(const bf16x8*)&kr[0];
    const bf16x8 a1 = *(const bf16x8*)&kr[32];
    f32x4 accQK[4] = {};
#pragma unroll
    for (int tt = 0; tt < 4; ++tt) {
      const unsigned short* qr = qu + rowbase + (size_t)(tt * 16 + fr) * QS + kh * 8;
      const bf16x8 b0 = *(const bf16x8*)&qr[0];
      const bf16x8 b1 = *(const bf16x8*)&qr[32];
      accQK[tt] = __builtin_amdgcn_mfma_f32_16x16x32_bf16(a0, b0, accQK[tt], 0, 0, 0);
      accQK[tt] = __builtin_amdgcn_mfma_f32_16x16x32_bf16(a1, b1, accQK[tt], 0, 0, 0);
    }
    // mask (keep s <= t), write hi/lo At[t][s], per-wave den partials
#pragma unroll
    for (int tt = 0; tt < 4; ++tt) {
      const int t = tt * 16 + fr;
      float dp = 0.f;
#pragma unroll
      for (int r = 0; r < 4; ++r) {
        const int s = w4 * 16 + kh * 4 + r;
        const float val = (s <= t) ? accQK[tt][r] : 0.f;
        const unsigned short hv = f2bf(val);
        Atb[t][s] = hv;
        Atl[t][s] = f2bf(val - bf2f(hv));
        dp += val;
      }
      dp += __shfl_xor(dp, 16);
      dp += __shfl_xor(dp, 32);
      if (ln < 16) denp[w4][t] = dp;
    }
  }
  __syncthreads();
  // --- den: qpk (q direct from global, sg-split) + denp sums ---
  {
    const int t = tid >> 2, sg = tid & 3;
    const float* pk = Ksum + (size_t)g * 64;
    const unsigned short* qr = qu + rowbase + (size_t)t * QS + sg * 16;
    float qpk = 0.f;
#pragma unroll
    for (int i = 0; i < 16; ++i) qpk = fmaf(bf2f(qr[i]), pk[sg * 16 + i], qpk);
    qpk += __shfl_xor(qpk, 1);
    qpk += __shfl_xor(qpk, 2);
    if (sg == 0)
      dens[t] = denp[0][t] + denp[1][t] + denp[2][t] + denp[3][t] + qpk + 1e-6f;
  }
  __syncthreads();
  // --- stage 2: num = At @ V + Q @ P via MFMA (hi+lo for At AND P) ---
  const int w = tid >> 6, ln = tid & 63;
  const int fr = ln & 15;
  const int kh = ln >> 4;
  const bf16x8 sa0 = *(const bf16x8*)&Atb[w * 16 + fr][kh * 8];
  const bf16x8 sa1 = *(const bf16x8*)&Atb[w * 16 + fr][kh * 8 + 32];
  const bf16x8 la0 = *(const bf16x8*)&Atl[w * 16 + fr][kh * 8];
  const bf16x8 la1 = *(const bf16x8*)&Atl[w * 16 + fr][kh * 8 + 32];
  const unsigned short* q2 = qu + rowbase + (size_t)(w * 16 + fr) * QS + kh * 8;
  const bf16x8 qa0 = *(const bf16x8*)&q2[0];
  const bf16x8 qa1 = *(const bf16x8*)&q2[32];
  f32x4 acc2[4] = {};
#pragma unroll
  for (int ct = 0; ct < 4; ++ct) {
    const bf16x8 vb0 = *(const bf16x8*)&Vt[ct * 16 + fr][kh * 8];
    const bf16x8 vb1 = *(const bf16x8*)&Vt[ct * 16 + fr][kh * 8 + 32];
    const bf16x8 ph0 = *(const bf16x8*)&Pth[ct * 16 + fr][kh * 8];
    const bf16x8 ph1 = *(const bf16x8*)&Pth[ct * 16 + fr][kh * 8 + 32];
    const bf16x8 pl0 = *(const bf16x8*)&Ptl[ct * 16 + fr][kh * 8];
    const bf16x8 pl1 = *(const bf16x8*)&Ptl[ct * 16 + fr][kh * 8 + 32];
    acc2[ct] = __builtin_amdgcn_mfma_f32_16x16x32_bf16(sa0, vb0, acc2[ct], 0, 0, 0);
    acc2[ct] = __builtin_amdgcn_mfma_f32_16x16x32_bf16(sa1, vb1, acc2[ct], 0, 0, 0);
    acc2[ct] = __builtin_amdgcn_mfma_f32_16x16x32_bf16(la0, vb0, acc2[ct], 0, 0, 0);
    acc2[ct] = __builtin_amdgcn_mfma_f32_16x16x32_bf16(la1, vb1, acc2[ct], 0, 0, 0);
    acc2[ct] = __builtin_amdgcn_mfma_f32_16x16x32_bf16(qa0, ph0, acc2[ct], 0, 0, 0);
    acc2[ct] = __builtin_amdgcn_mfma_f32_16x16x32_bf16(qa1, ph1, acc2[ct], 0, 0, 0);
    acc2[ct] = __builtin_amdgcn_mfma_f32_16x16x32_bf16(qa0, pl0, acc2[ct], 0, 0, 0);
    acc2[ct] = __builtin_amdgcn_mfma_f32_16x16x32_bf16(qa1, pl1, acc2[ct], 0, 0, 0);
  }
  // --- epilogue: divide by den, per-head LN (row t in 16 consecutive lanes) ---
  unsigned short* yb = (unsigned short*)yhb;
#pragma unroll
  for (int r = 0; r < 4; ++r) {
    const int t = w * 16 + kh * 4 + r;
    const float inv = 1.f / dens[t];
    float o[4];
    float s1 = 0.f, s2 = 0.f;
#pragma unroll
    for (int ct = 0; ct < 4; ++ct) {
      o[ct] = acc2[ct][r] * inv;
      s1 += o[ct];
      s2 += o[ct] * o[ct];
    }
#pragma unroll
    for (int m = 1; m < 16; m <<= 1) {
      s1 += __shfl_xor(s1, m);
      s2 += __shfl_xor(s2, m);
    }
    const float mean = s1 * (1.f / 64.f);
    const float var = s2 * (1.f / 64.f) - mean * mean;
    const float rsv = rsqrtf(var + 1e-5f);
    unsigned short* yg = yb + (size_t)(b * Tt + j * CHK + t) * Dd + h * DHh;
#pragma unroll
    for (int ct = 0; ct < 4; ++ct) {
      const int e = ct * 16 + fr;
      const float rr = (o[ct] - mean) * rsv * lnw[h * DHh + e] + lnb[h * DHh + e];
      yg[e] = f2bf(rr);
    }
  }
}

// ---------------------------------------------------------------------------
// Fused FFN2-reduce (4 bf16 split-K partials) + bias + relu + residual +
// final layernorm over D=1024.
// ---------------------------------------------------------------------------
__global__ __launch_bounds__(256) void final_ln(const float* __restrict__ x,
                                                const __hip_bfloat16* __restrict__ part,
                                                const float* __restrict__ b2,
                                                const float* __restrict__ w,
                                                const float* __restrict__ bb,
                                                float* __restrict__ out) {
  __shared__ float r1[4], r2[4];
  const int row = blockIdx.x;
  const int tid = threadIdx.x;
  const size_t off = (size_t)row * Dd + tid * 4;
  const size_t MN = (size_t)Mm * Dd;
  float acc4[4] = {0.f, 0.f, 0.f, 0.f};
#pragma unroll
  for (int z = 0; z < 4; ++z) {
    const ushort4 u = *(const ushort4*)&part[off + (size_t)z * MN];
    acc4[0] += bf2f(u.x);
    acc4[1] += bf2f(u.y);
    acc4[2] += bf2f(u.z);
    acc4[3] += bf2f(u.w);
  }
  const float4 bv = *(const float4*)&b2[tid * 4];
  const float4 xa = *(const float4*)&x[off];
  float z[4];
  z[0] = xa.x + fmaxf(acc4[0] + bv.x, 0.f);
  z[1] = xa.y + fmaxf(acc4[1] + bv.y, 0.f);
  z[2] = xa.z + fmaxf(acc4[2] + bv.z, 0.f);
  z[3] = xa.w + fmaxf(acc4[3] + bv.w, 0.f);
  float s1 = z[0] + z[1] + z[2] + z[3];
  float s2 = z[0] * z[0] + z[1] * z[1] + z[2] * z[2] + z[3] * z[3];
#pragma unroll
  for (int o = 1; o < 64; o <<= 1) {
    s1 += __shfl_xor(s1, o);
    s2 += __shfl_xor(s2, o);
  }
  const int wid = tid >> 6;
  if ((tid & 63) == 0) {
    r1[wid] = s1;
    r2[wid] = s2;
  }
  __syncthreads();
  const float t1 = r1[0] + r1[1] + r1[2] + r1[3];
  const float t2 = r2[0] + r2[1] + r2[2] + r2[3];
  const float mu = t1 * (1.f / Dd);
  const float var = t2 * (1.f / Dd) - mu * mu;
  const float rsv = rsqrtf(var + 1e-5f);
  float4 o4;
  float* op = &o4.x;
#pragma unroll
  for (int jj = 0; jj < 4; ++jj) op[jj] = (z[jj] - mu) * rsv * w[tid * 4 + jj] + bb[tid * 4 + jj];
  *(float4*)&out[off] = o4;
}

// ---------------------------------------------------------------------------
extern "C" void kernel_launch(void* const* d_in, const int* in_sizes, int n_in,
                              void* d_out, int out_size, void* d_ws, size_t ws_size,
                              hipStream_t stream) {
  const float* x = (const float*)d_in[0];
  const float* W_amp = (const float*)d_in[1];
  const float* b_amp = (const float*)d_in[2];
  const float* W_phi = (const float*)d_in[3];
  const float* b_phi = (const float*)d_in[4];
  const float* omega = (const float*)d_in[5];
  const float* ret_logit = (const float*)d_in[6];
  const float* theta = (const float*)d_in[7];
  const float* W_feat = (const float*)d_in[8];
  const float* b_feat = (const float*)d_in[9];
  const float* Wq = (const float*)d_in[10];
  const float* Wk = (const float*)d_in[11];
  const float* Wv = (const float*)d_in[12];
  const float* lnh_w = (const float*)d_in[13];
  const float* lnh_b = (const float*)d_in[14];
  const float* W1 = (const float*)d_in[15];
  const float* b1 = (const float*)d_in[16];
  const float* W2 = (const float*)d_in[17];
  const float* b2 = (const float*)d_in[18];
  const float* ln_w = (const float*)d_in[19];
  const float* ln_b = (const float*)d_in[20];

  // ---- workspace bump allocator (256B aligned); dedicated buffers ----
  char* p = (char*)d_ws;
  auto alloc = [&](size_t bytes) {
    char* r = p;
    p += (bytes + 255) & ~(size_t)255;
    return r;
  };
  __hip_bfloat16* xb = (__hip_bfloat16*)alloc((size_t)Mm * Dd * 2);   // later: featb
  __hip_bfloat16* urh = (__hip_bfloat16*)alloc((size_t)Mm * NFf * 2);
  __hip_bfloat16* uih = (__hip_bfloat16*)alloc((size_t)Mm * NFf * 2);
  __hip_bfloat16* WTamp = (__hip_bfloat16*)alloc((size_t)NFf * Dd * 2);  // +WTphi contiguous
  __hip_bfloat16* WTphi = (__hip_bfloat16*)alloc((size_t)NFf * Dd * 2);
  __hip_bfloat16* WTfeat = (__hip_bfloat16*)alloc((size_t)Dd * 3 * NFf * 2);
  __hip_bfloat16* WTq = (__hip_bfloat16*)alloc((size_t)Dd * Dd * 2);  // +k+v contiguous
  __hip_bfloat16* WTk = (__hip_bfloat16*)alloc((size_t)Dd * Dd * 2);
  __hip_bfloat16* WTv = (__hip_bfloat16*)alloc((size_t)Dd * Dd * 2);
  __hip_bfloat16* WT1 = (__hip_bfloat16*)alloc((size_t)Rr * Dd * 2);
  __hip_bfloat16* WT2 = (__hip_bfloat16*)alloc((size_t)Dd * Rr * 2);
  __hip_bfloat16* hb = (__hip_bfloat16*)alloc((size_t)Mm * Dd * 2);
  __hip_bfloat16* qkvb = (__hip_bfloat16*)alloc((size_t)Mm * QS * 2);  // 12 MB
  __hip_bfloat16* yhb = (__hip_bfloat16*)alloc((size_t)Mm * Dd * 2);   // 4 MB
  float* S = (float*)alloc((size_t)Bb * Hh * NCHK * 4096 * 4);         // 8 MB fp32 (r21)
  float* Ksum = (float*)alloc((size_t)Bb * Hh * NCHK * 64 * 4);
  __hip_bfloat16* f1b = (__hip_bfloat16*)alloc((size_t)Mm * Rr * 2);   // 16 MB
  __hip_bfloat16* pamp = (__hip_bfloat16*)alloc((size_t)4 * Mm * 512 * 2);   // 8 MB (split-4)
  __hip_bfloat16* pffn2 = (__hip_bfloat16*)alloc((size_t)4 * Mm * Dd * 2);   // 16 MB dedicated
  float* pfeat = (float*)alloc((size_t)2 * Mm * Dd * 4);               // 16 MB fp32 (r25)

  __hip_bfloat16* featb = xb;  // xb dead after ampphi GEMM (stream-ordered)
  const __hip_bfloat16* q = qkvb;
  const __hip_bfloat16* k = qkvb + 1024;
  const __hip_bfloat16* v = qkvb + 2048;
  float* out = (float*)d_out;

  const dim3 blk(256);

  // 0: amp/phi weight transposes + x cast (what the first GEMM needs)
  tc_first<<<dim3(2560), blk, 0, stream>>>(W_amp, W_phi, WTamp, WTphi, x, xb);

  // 1: fused amp/phi projection, split-K=4 (r23-proven numerics), then
  //    fused reduce + softplus/tanh + polar -> bf16 u
  gemm_mfma<EPI_NONE, 1, 4><<<dim3(512 / 128, Mm / 128, 4), blk, 0, stream>>>(
      (const short*)xb, (const short*)WTamp, nullptr, nullptr, pamp, Mm, 512, Dd);
  reduce_polar<<<dim3(Mm * NFf / 256), blk, 0, stream>>>(pamp, b_amp, b_phi, urh, uih);

  // 2: FUSED resonator scan (64 blocks) || remaining weight transposes
  STDesc st;
  st.src[0] = W_feat; st.dst[0] = WTfeat;
  st.src[1] = Wq; st.dst[1] = WTq;
  st.src[2] = Wk; st.dst[2] = WTk;
  st.src[3] = Wv; st.dst[3] = WTv;
  st.src[4] = W1; st.dst[4] = WT1;
  st.src[5] = W2; st.dst[5] = WT2;
  st.ur = urh; st.ui = uih;
  st.omega = omega; st.ret_logit = ret_logit; st.theta = theta;
  st.featb = featb;
  scan_and_tc<<<dim3(64 + 12032), blk, 0, stream>>>(st);

  // 3: feat projection, split-K=2 with FP32 partials (r25: sum-order-only,
  //    no added quantization at the pipeline head), then reduce+bias+relu
  gemm_mfma<EPI_NONE, 0, 2><<<dim3(Dd / 128, Mm / 128, 2), blk, 0, stream>>>(
      (const short*)featb, (const short*)WTfeat, nullptr, pfeat, nullptr, Mm, Dd, 3 * NFf);
  reduce_feat<<<dim3(Mm * Dd / 1024), blk, 0, stream>>>(pfeat, b_feat, hb);

  // 4: fused q,k,v projection -> bf16 qkvb (384 blocks)
  gemm_mfma<EPI_QKV, 1, 0><<<dim3(QS / 128, Mm / 128), blk, 0, stream>>>(
      (const short*)hb, (const short*)WTq, nullptr, nullptr, qkvb, Mm, QS, Dd);

  // 5: chunked causal linear attention (+ fused per-head LN in attn_out)
  attn_chunk_kv<<<dim3(Bb * Hh * NCHK), blk, 0, stream>>>(k, v, S, Ksum);
  attn_prefix<<<dim3(520), blk, 0, stream>>>(S, Ksum);
  attn_out<<<dim3(Bb * Hh * NCHK), blk, 0, stream>>>(q, k, v, S, Ksum, lnh_w, lnh_b, yhb);

  // 6: FFN1 -> f1b (bf16); 512 blocks = 2 blocks/CU (dbuf LDS cap)
  gemm_mfma<EPI_RELU, 1, 0><<<dim3(Rr / 128, Mm / 128), blk, 0, stream>>>(
      (const short*)yhb, (const short*)WT1, b1, nullptr, f1b, Mm, Rr, Dd);

  // 7: FFN2 split-K=4, bf16 partials -> pffn2; 512 blocks = 2 blocks/CU
  gemm_mfma<EPI_NONE, 1, 4><<<dim3(Dd / 128, Mm / 128, 4), blk, 0, stream>>>(
      (const short*)f1b, (const short*)WT2, nullptr, nullptr, pffn2, Mm, Dd, Rr);

  // 8: fused reduce(4x bf16) + bias + relu + residual + final layernorm
  final_ln<<<dim3(Mm), blk, 0, stream>>>(x, pffn2, b2, ln_w, ln_b, out);
}